// Round 3
// baseline (635.453 us; speedup 1.0000x reference)
//
#include <hip/hip_runtime.h>
#include <hip/hip_fp16.h>

#define N1 131072
#define E1 2097152
#define N2 2368
#define E2 37888
#define NROIS 148
#define BSZ 16
#define HID 64
#define INCH 128
#define NSEG (BSZ*NROIS)      /* 2368 */
#define SDIM (NROIS*HID)      /* 9472 */
#define CLS 1000
#define OCH 2

#define KT1 74                /* k tiles for k_cls */
#define KCC 128               /* k per tile (74*128 = 9472) */
#define CT1 4                 /* col tiles of 256 */

#define NB1 512               /* dst buckets for graph-1 partition */
#define BLK1 512              /* partition blocks */
#define EPB (E1/BLK1)         /* 4096 edges per block */
#define NPB (N1/NB1)          /* 256 nodes per bucket */

#define GB1 (N1/256)          /* 512 gemm blocks graph1 */
#define GB2 ((N2+255)/256)    /* 10 gemm blocks graph2 */
#define CB1 ((N1+3)/4)        /* 32768 conv blocks graph1 */
#define CB2 ((N2+3)/4)        /* 592 conv blocks graph2 */
#define PB  ((NSEG+3)/4)      /* 592 pool blocks per graph */

__device__ __forceinline__ unsigned packh2(float a, float b) {
    return (unsigned)__half_as_ushort(__float2half_rn(a)) |
           ((unsigned)__half_as_ushort(__float2half_rn(b)) << 16);
}

// fp32 acc += (f16 half of hb) * w  -- single VALU op, no unpack
__device__ __forceinline__ void fma_lo(float& a, unsigned hb, float w) {
    asm("v_fma_mix_f32 %0, %1, %2, %0 op_sel:[0,0,0] op_sel_hi:[1,0,0]"
        : "+v"(a) : "v"(hb), "v"(w));
}
__device__ __forceinline__ void fma_hi(float& a, unsigned hb, float w) {
    asm("v_fma_mix_f32 %0, %1, %2, %0 op_sel:[1,0,0] op_sel_hi:[1,0,0]"
        : "+v"(a) : "v"(hb), "v"(w));
}

// ---------------- generic small-graph CSR build ----------------

__global__ void k_hist_dst(int* __restrict__ cnt, const int* __restrict__ dst, int E) {
    int e = blockIdx.x * 256 + threadIdx.x;
    if (e < E) atomicAdd(&cnt[dst[e]], 1);
}

// fused over both graphs: thread i handles graph-1 item i or graph-2 item i-n1
__global__ void k_hist_seg2(int* __restrict__ c1, const int* __restrict__ b1,
                            const int* __restrict__ l1, int n1_,
                            int* __restrict__ c2, const int* __restrict__ b2,
                            const int* __restrict__ l2, int n2_) {
    int i = blockIdx.x * 256 + threadIdx.x;
    if (i < n1_) { atomicAdd(&c1[b1[i] * NROIS + l1[i]], 1); return; }
    int j = i - n1_;
    if (j < n2_) atomicAdd(&c2[b2[j] * NROIS + l2[j]], 1);
}

// multi-block exclusive scan (used for the obh bucket histogram)
__global__ void k_scan1(const int* __restrict__ in, int* __restrict__ out,
                        int* __restrict__ part, int n) {
    __shared__ int sh[256];
    int t = threadIdx.x;
    int i0 = blockIdx.x * 1024 + t * 4;
    int v0 = (i0     < n) ? in[i0]     : 0;
    int v1 = (i0 + 1 < n) ? in[i0 + 1] : 0;
    int v2 = (i0 + 2 < n) ? in[i0 + 2] : 0;
    int v3 = (i0 + 3 < n) ? in[i0 + 3] : 0;
    int tot = v0 + v1 + v2 + v3;
    sh[t] = tot; __syncthreads();
    for (int off = 1; off < 256; off <<= 1) {
        int x = 0; if (t >= off) x = sh[t - off];
        __syncthreads();
        if (t >= off) sh[t] += x;
        __syncthreads();
    }
    int excl = sh[t] - tot;
    if (t == 255) part[blockIdx.x] = sh[255];
    if (i0     < n) out[i0]     = excl;
    if (i0 + 1 < n) out[i0 + 1] = excl + v0;
    if (i0 + 2 < n) out[i0 + 2] = excl + v0 + v1;
    if (i0 + 3 < n) out[i0 + 3] = excl + v0 + v1 + v2;
}

__global__ void k_scan2(int* __restrict__ part, int cnt) {
    __shared__ int sh[256];
    int t = threadIdx.x;
    int v = (t < cnt) ? part[t] : 0;
    sh[t] = v; __syncthreads();
    for (int off = 1; off < 256; off <<= 1) {
        int x = 0; if (t >= off) x = sh[t - off];
        __syncthreads();
        if (t >= off) sh[t] += x;
        __syncthreads();
    }
    if (t < cnt) part[t] = sh[t] - v;
}

__global__ void k_scan3(int* __restrict__ out, const int* __restrict__ part, int n, int total) {
    int i = blockIdx.x * 256 + threadIdx.x;
    if (i < n) out[i] += part[i >> 10];
    if (i == 0) out[n] = total;
}

// single-block exclusive scan; block 0 scans set A, block 1 (if in1 != null) set B.
// out2 gets a second copy of the scan (replaces a D2D memcpy); may alias `in`.
__global__ void k_scan_one(const int* __restrict__ in0, int* __restrict__ out0,
                           int* __restrict__ oo0, int n0,
                           const int* __restrict__ in1, int* __restrict__ out1,
                           int* __restrict__ oo1, int n1_) {
    __shared__ int sh[256];
    __shared__ int carry;
    const int* in; int* out; int* oo; int n;
    if (blockIdx.x == 0) { in = in0; out = out0; oo = oo0; n = n0; }
    else { if (!in1) return; in = in1; out = out1; oo = oo1; n = n1_; }
    int t = threadIdx.x;
    if (t == 0) carry = 0;
    __syncthreads();
    for (int base = 0; base < n; base += 256) {
        int i = base + t;
        int v = (i < n) ? in[i] : 0;
        sh[t] = v; __syncthreads();
        for (int off = 1; off < 256; off <<= 1) {
            int x = 0; if (t >= off) x = sh[t - off];
            __syncthreads();
            if (t >= off) sh[t] += x;
            __syncthreads();
        }
        if (i < n) {
            int e = carry + sh[t] - v;
            out[i] = e;
            if (oo) oo[i] = e;
        }
        __syncthreads();
        if (t == 255) carry += sh[255];
        __syncthreads();
    }
    if (t == 0) out[n] = carry;
}

__global__ void k_fill_edges(int2* __restrict__ edges, int* __restrict__ off,
                             const int* __restrict__ src, const int* __restrict__ dst,
                             const float* __restrict__ ew, int E) {
    int e = blockIdx.x * 256 + threadIdx.x;
    if (e >= E) return;
    int pos = atomicAdd(&off[dst[e]], 1);
    edges[pos] = make_int2(src[e], __float_as_int(ew[e]));
}

__global__ void k_fill_seg2(int* __restrict__ id1, int* __restrict__ o1,
                            const int* __restrict__ b1, const int* __restrict__ l1, int n1_,
                            int* __restrict__ id2, int* __restrict__ o2,
                            const int* __restrict__ b2, const int* __restrict__ l2, int n2_) {
    int i = blockIdx.x * 256 + threadIdx.x;
    if (i < n1_) {
        int pos = atomicAdd(&o1[b1[i] * NROIS + l1[i]], 1);
        id1[pos] = i;
        return;
    }
    int j = i - n1_;
    if (j < n2_) {
        int pos = atomicAdd(&o2[b2[j] * NROIS + l2[j]], 1);
        id2[pos] = j;
    }
}

__global__ void k_deg_dinv(float* __restrict__ dinv, const int* __restrict__ row,
                           const int2* __restrict__ edges, int n) {
    int d = blockIdx.x * 256 + threadIdx.x;
    if (d >= n) return;
    int a = row[d], b = row[d + 1];
    float s = 1.0f;
    for (int i = a; i < b; i++) s += __int_as_float(edges[i].y);
    dinv[d] = rsqrtf(s);
}

__global__ void k_scale(int2* __restrict__ edges, const int* __restrict__ row,
                        const float* __restrict__ dinv, int n) {
    int d = blockIdx.x * 256 + threadIdx.x;
    if (d >= n) return;
    int a = row[d], b = row[d + 1];
    float dd = dinv[d];
    for (int i = a; i < b; i++) {
        int2 e = edges[i];
        edges[i].y = __float_as_int(dinv[e.x] * __int_as_float(e.y) * dd);
    }
}

// ---------------- graph-1 radix-partition CSR build ----------------

__global__ __launch_bounds__(256) void k_p1(int* __restrict__ bh, const int* __restrict__ dst) {
    __shared__ int cnt[NB1];
    int t = threadIdx.x, blk = blockIdx.x;
    for (int i = t; i < NB1; i += 256) cnt[i] = 0;
    __syncthreads();
    int base = blk * EPB;
    for (int i = t; i < EPB; i += 256) atomicAdd(&cnt[dst[base + i] >> 8], 1);
    __syncthreads();
    for (int b = t; b < NB1; b += 256) bh[b * BLK1 + blk] = cnt[b];   // bucket-major
}

// pack = src (17 bits) | dst_local (8 bits) << 17
__global__ __launch_bounds__(256) void k_p2(int2* __restrict__ tmp, const int* __restrict__ obh,
                                            const int* __restrict__ src,
                                            const int* __restrict__ dst,
                                            const float* __restrict__ ew) {
    __shared__ int cur[NB1];
    int t = threadIdx.x, blk = blockIdx.x;
    for (int b = t; b < NB1; b += 256) cur[b] = obh[b * BLK1 + blk];
    __syncthreads();
    int base = blk * EPB;
    for (int i = t; i < EPB; i += 256) {
        int e = base + i;
        int d = dst[e];
        int pos = atomicAdd(&cur[d >> 8], 1);
        tmp[pos] = make_int2(src[e] | ((d & 255) << 17), __float_as_int(ew[e]));
    }
}

// per-bucket histogram + weight sums; fused local exclusive scan produces row1
// directly (bucket base = obh[b*BLK1]) -- replaces the 3-dispatch N1 scan chain.
__global__ __launch_bounds__(256) void k_p3a(int* __restrict__ row1, float* __restrict__ dinv,
                                             const int2* __restrict__ tmp,
                                             const int* __restrict__ obh) {
    __shared__ int h[NPB];
    __shared__ float ws[NPB];
    __shared__ int sc[256];
    int t = threadIdx.x, b = blockIdx.x;
    h[t] = 0; ws[t] = 0.f;                 // NPB == 256 == blockDim
    __syncthreads();
    int ebase = obh[b * BLK1];
    int eend  = (b == NB1 - 1) ? E1 : obh[(b + 1) * BLK1];
    for (int i = ebase + t; i < eend; i += 256) {
        int2 ed = tmp[i];
        int dl = (ed.x >> 17) & 255;
        atomicAdd(&h[dl], 1);
        atomicAdd(&ws[dl], __int_as_float(ed.y));
    }
    __syncthreads();
    int cnt = h[t];
    sc[t] = cnt; __syncthreads();
    for (int off = 1; off < 256; off <<= 1) {
        int x = 0; if (t >= off) x = sc[t - off];
        __syncthreads();
        if (t >= off) sc[t] += x;
        __syncthreads();
    }
    row1[b * NPB + t] = ebase + sc[t] - cnt;
    dinv[b * NPB + t] = rsqrtf(1.f + ws[t]);
    if (b == NB1 - 1 && t == 255) row1[N1] = E1;
}

__global__ __launch_bounds__(256) void k_p3b(int2* __restrict__ edges,
                                             const int2* __restrict__ tmp,
                                             const int* __restrict__ obh,
                                             const int* __restrict__ row,
                                             const float* __restrict__ dinv) {
    __shared__ int cur[NPB];
    __shared__ float dvl[NPB];
    int t = threadIdx.x, b = blockIdx.x;
    int n0 = b * NPB;
    for (int i = t; i < NPB; i += 256) {
        cur[i] = row[n0 + i];
        dvl[i] = dinv[n0 + i];
    }
    __syncthreads();
    int a  = obh[b * BLK1];
    int e_ = (b == NB1 - 1) ? E1 : obh[(b + 1) * BLK1];
    for (int i = a + t; i < e_; i += 256) {
        int2 ed = tmp[i];
        int dl = (ed.x >> 17) & 255;
        int s = ed.x & 0x1FFFF;
        int pos = atomicAdd(&cur[dl], 1);
        float w = dinv[s] * __int_as_float(ed.y) * dvl[dl];
        edges[pos] = make_int2(s, __float_as_int(w));
    }
}

// ---------------- dense ops ----------------

__device__ __forceinline__ float4 ldx(const float* x, size_t idx) {
    return *(const float4*)(x + idx);
}
__device__ __forceinline__ float4 ldx(const __half* x, size_t idx) {
    uint2 u = *(const uint2*)(x + idx);
    __half2 a = *(__half2*)&u.x, b = *(__half2*)&u.y;
    float2 fa = __half22float2(a), fb = __half22float2(b);
    return make_float4(fa.x, fa.y, fb.x, fb.y);
}

// out_f16[n][64] = x[n][K] @ W[K][64], fused over both graphs by block range.
template <int K, typename T>
__global__ __launch_bounds__(256) void k_gemm(__half* __restrict__ out1, const T* __restrict__ x1,
                                              const float* __restrict__ W1, int n1_,
                                              __half* __restrict__ out2, const T* __restrict__ x2,
                                              const float* __restrict__ W2, int n2_, int split) {
    __shared__ float Wl[32 * 64];       // [kk][col]
    __shared__ float xs[256 * 37];      // [r][kk], stride 37
    int tid = threadIdx.x;
    __half* out; const T* x; const float* W; int n; int row0;
    if ((int)blockIdx.x < split) { out = out1; x = x1; W = W1; n = n1_; row0 = blockIdx.x * 256; }
    else { out = out2; x = x2; W = W2; n = n2_; row0 = (blockIdx.x - split) * 256; }
    int r0 = (tid >> 3) * 8;
    int c0 = (tid & 7) * 8;
    float acc[8][8];
#pragma unroll
    for (int i = 0; i < 8; i++)
#pragma unroll
        for (int j = 0; j < 8; j++) acc[i][j] = 0.f;

    for (int k0 = 0; k0 < K; k0 += 32) {
        __syncthreads();
        {
            const float4* W4 = (const float4*)(W + k0 * 64);
            float4* Wl4 = (float4*)Wl;
#pragma unroll
            for (int i = 0; i < 2; i++) Wl4[tid + i * 256] = W4[tid + i * 256];
        }
#pragma unroll
        for (int i = 0; i < 8; i++) {
            int idx = tid + i * 256;
            int r = idx >> 3, kq = idx & 7;
            float4 v = make_float4(0.f, 0.f, 0.f, 0.f);
            if (row0 + r < n)
                v = ldx(x, (size_t)(row0 + r) * K + k0 + kq * 4);
            xs[r * 37 + kq * 4 + 0] = v.x;
            xs[r * 37 + kq * 4 + 1] = v.y;
            xs[r * 37 + kq * 4 + 2] = v.z;
            xs[r * 37 + kq * 4 + 3] = v.w;
        }
        __syncthreads();
#pragma unroll 2
        for (int kk = 0; kk < 32; kk++) {
            float4 wlo = *(const float4*)(&Wl[kk * 64 + c0]);
            float4 whi = *(const float4*)(&Wl[kk * 64 + c0 + 4]);
            float xf[8];
#pragma unroll
            for (int i = 0; i < 8; i++) xf[i] = xs[(r0 + i) * 37 + kk];
#pragma unroll
            for (int i = 0; i < 8; i++) {
                acc[i][0] += xf[i] * wlo.x; acc[i][1] += xf[i] * wlo.y;
                acc[i][2] += xf[i] * wlo.z; acc[i][3] += xf[i] * wlo.w;
                acc[i][4] += xf[i] * whi.x; acc[i][5] += xf[i] * whi.y;
                acc[i][6] += xf[i] * whi.z; acc[i][7] += xf[i] * whi.w;
            }
        }
    }
#pragma unroll
    for (int i = 0; i < 8; i++) {
        int row = row0 + r0 + i;
        if (row < n) {
            uint4 o;
            o.x = packh2(acc[i][0], acc[i][1]);
            o.y = packh2(acc[i][2], acc[i][3]);
            o.z = packh2(acc[i][4], acc[i][5]);
            o.w = packh2(acc[i][6], acc[i][7]);
            *(uint4*)(out + (size_t)row * 64 + c0) = o;
        }
    }
}

// fused GCN aggregate v4: wave per dst node, 4 edge-slots x 16 lanes.
// No shuffles: each 16-lane group loads its edge record directly (same-address
// broadcast, L1/L2-resident since edges stream sequentially) -- removes all
// ds_bpermute + lgkm stalls. fp16 h consumed via v_fma_mix_f32 (no unpack ops).
// 4 edges/thread/iter = 4 independent load chains, ~2 KB/wave in flight.
__device__ __forceinline__ void conv_core(__half* __restrict__ out, const __half* __restrict__ h,
                                          const int2* __restrict__ edges,
                                          const int* __restrict__ row,
                                          const float* __restrict__ dinv,
                                          const float* __restrict__ bias, int d, int lane) {
    int slot = lane >> 4;         // edge slot 0..3
    int f4 = lane & 15;           // features f4*4 .. f4*4+3
    const __half* hb = h + f4 * 4;
    int a = row[d], b = row[d + 1];
    float acc[4][4];
#pragma unroll
    for (int k = 0; k < 4; k++)
#pragma unroll
        for (int f = 0; f < 4; f++) acc[k][f] = 0.f;

    int i = a;
    for (; i + 16 <= b; i += 16) {
#pragma unroll
        for (int k = 0; k < 4; k++) {
            int2 e = edges[i + 4 * k + slot];
            float w = __int_as_float(e.y);
            uint2 hv = *(const uint2*)(hb + (size_t)e.x * HID);
            fma_lo(acc[k][0], hv.x, w); fma_hi(acc[k][1], hv.x, w);
            fma_lo(acc[k][2], hv.y, w); fma_hi(acc[k][3], hv.y, w);
        }
    }
    if (i < b) {                  // masked tail (up to 15 edges)
#pragma unroll
        for (int k = 0; k < 4; k++) {
            int idx = i + 4 * k + slot;
            int2 e = edges[min(idx, b - 1)];
            float w = (idx < b) ? __int_as_float(e.y) : 0.f;
            uint2 hv = *(const uint2*)(hb + (size_t)e.x * HID);
            fma_lo(acc[k][0], hv.x, w); fma_hi(acc[k][1], hv.x, w);
            fma_lo(acc[k][2], hv.y, w); fma_hi(acc[k][3], hv.y, w);
        }
    }
    float r0 = (acc[0][0] + acc[1][0]) + (acc[2][0] + acc[3][0]);
    float r1 = (acc[0][1] + acc[1][1]) + (acc[2][1] + acc[3][1]);
    float r2 = (acc[0][2] + acc[1][2]) + (acc[2][2] + acc[3][2]);
    float r3 = (acc[0][3] + acc[1][3]) + (acc[2][3] + acc[3][3]);
    r0 += __shfl_xor(r0, 16); r0 += __shfl_xor(r0, 32);
    r1 += __shfl_xor(r1, 16); r1 += __shfl_xor(r1, 32);
    r2 += __shfl_xor(r2, 16); r2 += __shfl_xor(r2, 32);
    r3 += __shfl_xor(r3, 16); r3 += __shfl_xor(r3, 32);
    if (slot == 0) {
        float di = dinv[d];
        float sl = di * di;
        uint2 hd = *(const uint2*)(hb + (size_t)d * HID);
        fma_lo(r0, hd.x, sl); fma_hi(r1, hd.x, sl);
        fma_lo(r2, hd.y, sl); fma_hi(r3, hd.y, sl);
        float4 bb = *(const float4*)(bias + f4 * 4);
        r0 = fmaxf(r0 + bb.x, 0.f);
        r1 = fmaxf(r1 + bb.y, 0.f);
        r2 = fmaxf(r2 + bb.z, 0.f);
        r3 = fmaxf(r3 + bb.w, 0.f);
        uint2 ov;
        ov.x = packh2(r0, r1);
        ov.y = packh2(r2, r3);
        *(uint2*)(out + (size_t)d * HID + f4 * 4) = ov;
    }
}

__global__ __launch_bounds__(256) void k_conv(__half* __restrict__ o1, const __half* __restrict__ h1,
                                              const int2* __restrict__ e1, const int* __restrict__ r1,
                                              const float* __restrict__ dv1, const float* __restrict__ bi1,
                                              int n1_, int nb1_,
                                              __half* __restrict__ o2, const __half* __restrict__ h2,
                                              const int2* __restrict__ e2, const int* __restrict__ r2,
                                              const float* __restrict__ dv2, const float* __restrict__ bi2,
                                              int n2_) {
    int blk = blockIdx.x;
    int lane = threadIdx.x & 63;
    int w = threadIdx.x >> 6;
    if (blk < nb1_) {
        int d = blk * 4 + w;
        if (d < n1_) conv_core(o1, h1, e1, r1, dv1, bi1, d, lane);
    } else {
        int d = (blk - nb1_) * 4 + w;
        if (d < n2_) conv_core(o2, h2, e2, r2, dv2, bi2, d, lane);
    }
}

// segment-mean pool v3: same structure as conv v4 (direct nodeid loads,
// fma_mix with w=1 valid / w=0 masked), fp16 rows in, fp32 means out.
__device__ __forceinline__ void pool_core(float* __restrict__ emb, const __half* __restrict__ h,
                                          const int* __restrict__ nodeid,
                                          const int* __restrict__ segrow, int s, int lane) {
    int slot = lane >> 4;
    int f4 = lane & 15;
    const __half* hb = h + f4 * 4;
    int a = segrow[s], b = segrow[s + 1];
    float acc[4][4];
#pragma unroll
    for (int k = 0; k < 4; k++)
#pragma unroll
        for (int f = 0; f < 4; f++) acc[k][f] = 0.f;

    int i = a;
    for (; i + 16 <= b; i += 16) {
#pragma unroll
        for (int k = 0; k < 4; k++) {
            int q = nodeid[i + 4 * k + slot];
            uint2 hv = *(const uint2*)(hb + (size_t)q * HID);
            fma_lo(acc[k][0], hv.x, 1.f); fma_hi(acc[k][1], hv.x, 1.f);
            fma_lo(acc[k][2], hv.y, 1.f); fma_hi(acc[k][3], hv.y, 1.f);
        }
    }
    if (i < b) {
#pragma unroll
        for (int k = 0; k < 4; k++) {
            int idx = i + 4 * k + slot;
            int q = nodeid[min(idx, b - 1)];
            float w = (idx < b) ? 1.f : 0.f;
            uint2 hv = *(const uint2*)(hb + (size_t)q * HID);
            fma_lo(acc[k][0], hv.x, w); fma_hi(acc[k][1], hv.x, w);
            fma_lo(acc[k][2], hv.y, w); fma_hi(acc[k][3], hv.y, w);
        }
    }
    float r0 = (acc[0][0] + acc[1][0]) + (acc[2][0] + acc[3][0]);
    float r1 = (acc[0][1] + acc[1][1]) + (acc[2][1] + acc[3][1]);
    float r2 = (acc[0][2] + acc[1][2]) + (acc[2][2] + acc[3][2]);
    float r3 = (acc[0][3] + acc[1][3]) + (acc[2][3] + acc[3][3]);
    r0 += __shfl_xor(r0, 16); r0 += __shfl_xor(r0, 32);
    r1 += __shfl_xor(r1, 16); r1 += __shfl_xor(r1, 32);
    r2 += __shfl_xor(r2, 16); r2 += __shfl_xor(r2, 32);
    r3 += __shfl_xor(r3, 16); r3 += __shfl_xor(r3, 32);
    if (slot == 0) {
        float inv = 1.0f / fmaxf((float)(b - a), 1.0f);
        float4 mv = make_float4(r0 * inv, r1 * inv, r2 * inv, r3 * inv);
        *(float4*)(emb + (size_t)s * HID + f4 * 4) = mv;
    }
}

__global__ __launch_bounds__(256) void k_pool(float* __restrict__ em1, const __half* __restrict__ h1,
                                              const int* __restrict__ id1, const int* __restrict__ sr1,
                                              int nbs,
                                              float* __restrict__ em2, const __half* __restrict__ h2,
                                              const int* __restrict__ id2, const int* __restrict__ sr2) {
    int blk = blockIdx.x;
    int lane = threadIdx.x & 63;
    int w = threadIdx.x >> 6;
    if (blk < nbs) {
        int s = blk * 4 + w;
        if (s < NSEG) pool_core(em1, h1, id1, sr1, s, lane);
    } else {
        int s = (blk - nbs) * 4 + w;
        if (s < NSEG) pool_core(em2, h2, id2, sr2, s, lane);
    }
}

// ---------------- classifier ----------------

// computes s = emb1 + emb2 inline; ct==0 blocks also persist esum.
__global__ __launch_bounds__(256) void k_cls(float* __restrict__ part_,
                                             const float* __restrict__ e1,
                                             const float* __restrict__ e2,
                                             float* __restrict__ esum,
                                             const float* __restrict__ Wm1) {
    __shared__ float sl[KCC * 16];      // [kk][b]
    int tid = threadIdx.x;
    int kt = blockIdx.x >> 2, ct = blockIdx.x & 3;
    int k0 = kt * KCC;
    bool wr = (ct == 0);
    for (int i = tid; i < KCC * 16; i += 256) {
        int kk = i & (KCC - 1), b = i >> 7;        // coalesced over kk
        int idx = b * SDIM + k0 + kk;
        float v = e1[idx] + e2[idx];
        sl[kk * 16 + b] = v;
        if (wr) esum[idx] = v;
    }
    __syncthreads();
    int c = ct * 256 + tid;
    bool active = c < CLS;
    float acc[16];
#pragma unroll
    for (int b = 0; b < 16; b++) acc[b] = 0.f;
    const float* wp = Wm1 + (size_t)k0 * CLS + c;
#pragma unroll 2
    for (int kk = 0; kk < KCC; kk++) {
        float w = active ? wp[(size_t)kk * CLS] : 0.f;
        float4 s0 = *(const float4*)(&sl[kk * 16 + 0]);
        float4 s1 = *(const float4*)(&sl[kk * 16 + 4]);
        float4 s2 = *(const float4*)(&sl[kk * 16 + 8]);
        float4 s3 = *(const float4*)(&sl[kk * 16 + 12]);
        acc[0]  += s0.x * w; acc[1]  += s0.y * w; acc[2]  += s0.z * w; acc[3]  += s0.w * w;
        acc[4]  += s1.x * w; acc[5]  += s1.y * w; acc[6]  += s1.z * w; acc[7]  += s1.w * w;
        acc[8]  += s2.x * w; acc[9]  += s2.y * w; acc[10] += s2.z * w; acc[11] += s2.w * w;
        acc[12] += s3.x * w; acc[13] += s3.y * w; acc[14] += s3.z * w; acc[15] += s3.w * w;
    }
    float* pp = part_ + (size_t)(kt * CT1 + ct) * 16 * 256;
#pragma unroll
    for (int b = 0; b < 16; b++) pp[b * 256 + tid] = acc[b];
}

// reduce partials + BatchNorm + LeakyReLU in one pass
__global__ void k_credbn(float* __restrict__ hact, const float* __restrict__ part_,
                         const float* __restrict__ bm1, const float* __restrict__ gamma,
                         const float* __restrict__ beta, const float* __restrict__ mean,
                         const float* __restrict__ var) {
    int idx = blockIdx.x * 256 + threadIdx.x;
    if (idx >= BSZ * CLS) return;
    int b = idx / CLS, c = idx % CLS;
    int ct = c >> 8, cl = c & 255;
    float sum = 0.f;
#pragma unroll 2
    for (int kt = 0; kt < KT1; kt++)
        sum += part_[((size_t)(kt * CT1 + ct) * 16 + b) * 256 + cl];
    float t = sum + bm1[c];
    t = gamma[c] * (t - mean[c]) * rsqrtf(var[c] + 1e-5f) + beta[c];
    hact[idx] = t > 0.f ? t : 0.01f * t;
}

// one block per batch row; 128 partials per output
__global__ void k_out(float* __restrict__ outp, const float* __restrict__ hact,
                      const float* __restrict__ Wm2, const float* __restrict__ bm2) {
    int b = blockIdx.x;
    int tid = threadIdx.x;
    int o = tid & 1, part = tid >> 1;   // 2 outputs x 128 partials
    float acc = (part == 0) ? bm2[o] : 0.f;
    for (int k = part; k < CLS; k += 128) acc += hact[b * CLS + k] * Wm2[k * OCH + o];
    unsafeAtomicAdd(&outp[b * OCH + o], acc);
}

extern "C" void kernel_launch(void* const* d_in, const int* in_sizes, int n_in,
                              void* d_out, int out_size, void* d_ws, size_t ws_size,
                              hipStream_t stream) {
    const float* x1  = (const float*)d_in[0];
    const int*   nl  = (const int*)d_in[1];
    const int*   ei1 = (const int*)d_in[2];
    const float* ew1 = (const float*)d_in[3];
    const int*   ba1 = (const int*)d_in[4];
    const float* x2  = (const float*)d_in[5];
    const int*   rl  = (const int*)d_in[6];
    const int*   ei2 = (const int*)d_in[7];
    const float* ew2 = (const float*)d_in[8];
    const int*   ba2 = (const int*)d_in[9];
    const float* W1a = (const float*)d_in[10];
    const float* b1a = (const float*)d_in[11];
    const float* W1b = (const float*)d_in[12];
    const float* b1b = (const float*)d_in[13];
    const float* W2a = (const float*)d_in[14];
    const float* b2a = (const float*)d_in[15];
    const float* W2b = (const float*)d_in[16];
    const float* b2b = (const float*)d_in[17];
    const float* Wm1 = (const float*)d_in[18];
    const float* bm1 = (const float*)d_in[19];
    const float* gam = (const float*)d_in[20];
    const float* bet = (const float*)d_in[21];
    const float* bmn = (const float*)d_in[22];
    const float* bvr = (const float*)d_in[23];
    const float* Wm2 = (const float*)d_in[24];
    const float* bm2 = (const float*)d_in[25];

    float* out  = (float*)d_out;
    float* emb1 = out + 32;               // embedding        (16 x 9472)
    float* emb2 = emb1 + NSEG * HID;      // embedding_roi
    float* esum = emb2 + NSEG * HID;      // embedding + embedding_roi

    // ---- workspace carve ----
    char* p = (char*)d_ws;
    auto carve = [&](size_t nbytes) { char* q = p; p += (nbytes + 255) & ~(size_t)255; return (void*)q; };
    int*    row1    = (int*)   carve((N1 + 1) * 4);
    int2*   edges1  = (int2*)  carve((size_t)E1 * 8);
    float*  dinv1   = (float*) carve(N1 * 4);
    __half* A1h     = (__half*)carve((size_t)N1 * HID * 2);   // fp16 h (gemm out)
    __half* B1h     = (__half*)carve((size_t)N1 * HID * 2);   // fp16 conv out
    int*    nodeid1 = (int*)   carve(N1 * 4);
    int*    segrow1 = (int*)   carve((NSEG + 1) * 4);
    int*    segoff  = (int*)   carve(2 * NSEG * 4);           // [0..NSEG) g1, [NSEG..) g2
    int*    bh      = (int*)   carve((NB1 * BLK1 + 1) * 4);
    int*    obh     = (int*)   carve((NB1 * BLK1 + 1) * 4);
    int*    row2    = (int*)   carve((N2 + 1) * 4);
    int*    off2    = (int*)   carve(N2 * 4);
    int2*   edges2  = (int2*)  carve((size_t)E2 * 8);
    float*  dinv2   = (float*) carve(N2 * 4);
    __half* A2h     = (__half*)carve((size_t)N2 * HID * 2);
    __half* B2h     = (__half*)carve((size_t)N2 * HID * 2);
    int*    nodeid2 = (int*)   carve(N2 * 4);
    int*    segrow2 = (int*)   carve((NSEG + 1) * 4);
    int*    part    = (int*)   carve(256 * 4);
    float*  hact    = (float*) carve(BSZ * CLS * 4);
    int*    segoff1 = segoff;
    int*    segoff2 = segoff + NSEG;
    int2*  tmp1 = (int2*)B1h;   // 16.8 MB aliases B1h (16.8 MB): CSR build done
                                // before conv1's first B1h write
    float* clsp = (float*)B1h;  // 4.85 MB partial slabs alias B1h: dead after pool

    const int* src1 = ei1;
    const int* dst1 = ei1 + E1;
    const int* src2 = ei2;
    const int* dst2 = ei2 + E2;

    hipMemsetAsync(d_out, 0, (size_t)out_size * sizeof(float), stream);

    // ---------------- graph 2 CSR (small) ----------------
    hipMemsetAsync(off2, 0, N2 * 4, stream);
    k_hist_dst<<<(E2 + 255) / 256, 256, 0, stream>>>(off2, dst2, E2);
    k_scan_one<<<1, 256, 0, stream>>>(off2, row2, off2, N2, nullptr, nullptr, nullptr, 0);
    k_fill_edges<<<(E2 + 255) / 256, 256, 0, stream>>>(edges2, off2, src2, dst2, ew2, E2);
    k_deg_dinv<<<(N2 + 255) / 256, 256, 0, stream>>>(dinv2, row2, edges2, N2);
    k_scale<<<(N2 + 255) / 256, 256, 0, stream>>>(edges2, row2, dinv2, N2);

    // ---------------- graph 1 CSR: radix-partition build ----------------
    k_p1<<<BLK1, 256, 0, stream>>>(bh, dst1);
    k_scan1<<<(NB1 * BLK1 + 1023) / 1024, 256, 0, stream>>>(bh, obh, part, NB1 * BLK1);
    k_scan2<<<1, 256, 0, stream>>>(part, (NB1 * BLK1 + 1023) / 1024);
    k_scan3<<<(NB1 * BLK1 + 255) / 256, 256, 0, stream>>>(obh, part, NB1 * BLK1, E1);
    k_p2<<<BLK1, 256, 0, stream>>>(tmp1, obh, src1, dst1, ew1);
    k_p3a<<<NB1, 256, 0, stream>>>(row1, dinv1, tmp1, obh);      // row1 built in-kernel
    k_p3b<<<NB1, 256, 0, stream>>>(edges1, tmp1, obh, row1, dinv1);

    // ---------------- fused dense pipeline (both graphs per dispatch) ----------------
    k_gemm<INCH, float><<<GB1 + GB2, 256, 0, stream>>>(A1h, x1, W1a, N1, A2h, x2, W2a, N2, GB1);
    k_conv<<<CB1 + CB2, 256, 0, stream>>>(B1h, A1h, edges1, row1, dinv1, b1a, N1, CB1,
                                          B2h, A2h, edges2, row2, dinv2, b2a, N2);
    k_gemm<HID, __half><<<GB1 + GB2, 256, 0, stream>>>(A1h, B1h, W1b, N1, A2h, B2h, W2b, N2, GB1);
    k_conv<<<CB1 + CB2, 256, 0, stream>>>(B1h, A1h, edges1, row1, dinv1, b1b, N1, CB1,
                                          B2h, A2h, edges2, row2, dinv2, b2b, N2);

    // ---------------- segment CSR + pool (both graphs) ----------------
    hipMemsetAsync(segoff, 0, 2 * NSEG * 4, stream);
    k_hist_seg2<<<(N1 + N2 + 255) / 256, 256, 0, stream>>>(segoff1, ba1, nl, N1,
                                                           segoff2, ba2, rl, N2);
    k_scan_one<<<2, 256, 0, stream>>>(segoff1, segrow1, segoff1, NSEG,
                                      segoff2, segrow2, segoff2, NSEG);
    k_fill_seg2<<<(N1 + N2 + 255) / 256, 256, 0, stream>>>(nodeid1, segoff1, ba1, nl, N1,
                                                           nodeid2, segoff2, ba2, rl, N2);
    k_pool<<<PB + PB, 256, 0, stream>>>(emb1, B1h, nodeid1, segrow1, PB,
                                        emb2, B2h, nodeid2, segrow2);
    // B1h dead from here; clsp aliases it

    // ---------------- classifier ----------------
    k_cls<<<KT1 * CT1, 256, 0, stream>>>(clsp, emb1, emb2, esum, Wm1);
    k_credbn<<<(BSZ * CLS + 255) / 256, 256, 0, stream>>>(hact, clsp, bm1, gam, bet, bmn, bvr);
    k_out<<<BSZ, 256, 0, stream>>>(out, hact, Wm2, bm2);
}

// Round 4
// 598.037 us; speedup vs baseline: 1.0626x; 1.0626x over previous
//
#include <hip/hip_runtime.h>
#include <hip/hip_fp16.h>

#define N1 131072
#define E1 2097152
#define N2 2368
#define E2 37888
#define NROIS 148
#define BSZ 16
#define HID 64
#define INCH 128
#define NSEG (BSZ*NROIS)      /* 2368 */
#define SDIM (NROIS*HID)      /* 9472 */
#define CLS 1000
#define OCH 2

#define KT1 74                /* k tiles for k_cls */
#define KCC 128               /* k per tile (74*128 = 9472) */
#define CT1 4                 /* col tiles of 256 */

#define NB1 512               /* dst buckets for graph-1 partition */
#define BLK1 512              /* partition blocks */
#define EPB (E1/BLK1)         /* 4096 edges per block */
#define NPB (N1/NB1)          /* 256 nodes per bucket */

#define GB1 (N1/256)          /* 512 gemm blocks graph1 */
#define GB2 ((N2+255)/256)    /* 10 gemm blocks graph2 */
#define CB1 ((N1+3)/4)        /* 32768 conv blocks graph1 */
#define CB2 ((N2+3)/4)        /* 592 conv blocks graph2 */
#define PB  ((NSEG+3)/4)      /* 592 pool blocks per graph */

__device__ __forceinline__ unsigned packh2(float a, float b) {
    return (unsigned)__half_as_ushort(__float2half_rn(a)) |
           ((unsigned)__half_as_ushort(__float2half_rn(b)) << 16);
}

// fp32 acc += (f16 half of hb) * w  -- single VALU op, no unpack
__device__ __forceinline__ void fma_lo(float& a, unsigned hb, float w) {
    asm("v_fma_mix_f32 %0, %1, %2, %0 op_sel:[0,0,0] op_sel_hi:[1,0,0]"
        : "+v"(a) : "v"(hb), "v"(w));
}
__device__ __forceinline__ void fma_hi(float& a, unsigned hb, float w) {
    asm("v_fma_mix_f32 %0, %1, %2, %0 op_sel:[1,0,0] op_sel_hi:[1,0,0]"
        : "+v"(a) : "v"(hb), "v"(w));
}

// ---------------- generic small-graph CSR build ----------------

__global__ void k_hist_dst(int* __restrict__ cnt, const int* __restrict__ dst, int E) {
    int e = blockIdx.x * 256 + threadIdx.x;
    if (e < E) atomicAdd(&cnt[dst[e]], 1);
}

// fused over both graphs: thread i handles graph-1 item i or graph-2 item i-n1
__global__ void k_hist_seg2(int* __restrict__ c1, const int* __restrict__ b1,
                            const int* __restrict__ l1, int n1_,
                            int* __restrict__ c2, const int* __restrict__ b2,
                            const int* __restrict__ l2, int n2_) {
    int i = blockIdx.x * 256 + threadIdx.x;
    if (i < n1_) { atomicAdd(&c1[b1[i] * NROIS + l1[i]], 1); return; }
    int j = i - n1_;
    if (j < n2_) atomicAdd(&c2[b2[j] * NROIS + l2[j]], 1);
}

// multi-block exclusive scan (used for the obh bucket histogram)
__global__ void k_scan1(const int* __restrict__ in, int* __restrict__ out,
                        int* __restrict__ part, int n) {
    __shared__ int sh[256];
    int t = threadIdx.x;
    int i0 = blockIdx.x * 1024 + t * 4;
    int v0 = (i0     < n) ? in[i0]     : 0;
    int v1 = (i0 + 1 < n) ? in[i0 + 1] : 0;
    int v2 = (i0 + 2 < n) ? in[i0 + 2] : 0;
    int v3 = (i0 + 3 < n) ? in[i0 + 3] : 0;
    int tot = v0 + v1 + v2 + v3;
    sh[t] = tot; __syncthreads();
    for (int off = 1; off < 256; off <<= 1) {
        int x = 0; if (t >= off) x = sh[t - off];
        __syncthreads();
        if (t >= off) sh[t] += x;
        __syncthreads();
    }
    int excl = sh[t] - tot;
    if (t == 255) part[blockIdx.x] = sh[255];
    if (i0     < n) out[i0]     = excl;
    if (i0 + 1 < n) out[i0 + 1] = excl + v0;
    if (i0 + 2 < n) out[i0 + 2] = excl + v0 + v1;
    if (i0 + 3 < n) out[i0 + 3] = excl + v0 + v1 + v2;
}

__global__ void k_scan2(int* __restrict__ part, int cnt) {
    __shared__ int sh[256];
    int t = threadIdx.x;
    int v = (t < cnt) ? part[t] : 0;
    sh[t] = v; __syncthreads();
    for (int off = 1; off < 256; off <<= 1) {
        int x = 0; if (t >= off) x = sh[t - off];
        __syncthreads();
        if (t >= off) sh[t] += x;
        __syncthreads();
    }
    if (t < cnt) part[t] = sh[t] - v;
}

__global__ void k_scan3(int* __restrict__ out, const int* __restrict__ part, int n, int total) {
    int i = blockIdx.x * 256 + threadIdx.x;
    if (i < n) out[i] += part[i >> 10];
    if (i == 0) out[n] = total;
}

// single-block exclusive scan; block 0 scans set A, block 1 (if in1 != null) set B.
// out2 gets a second copy of the scan (replaces a D2D memcpy); may alias `in`.
__global__ void k_scan_one(const int* __restrict__ in0, int* __restrict__ out0,
                           int* __restrict__ oo0, int n0,
                           const int* __restrict__ in1, int* __restrict__ out1,
                           int* __restrict__ oo1, int n1_) {
    __shared__ int sh[256];
    __shared__ int carry;
    const int* in; int* out; int* oo; int n;
    if (blockIdx.x == 0) { in = in0; out = out0; oo = oo0; n = n0; }
    else { if (!in1) return; in = in1; out = out1; oo = oo1; n = n1_; }
    int t = threadIdx.x;
    if (t == 0) carry = 0;
    __syncthreads();
    for (int base = 0; base < n; base += 256) {
        int i = base + t;
        int v = (i < n) ? in[i] : 0;
        sh[t] = v; __syncthreads();
        for (int off = 1; off < 256; off <<= 1) {
            int x = 0; if (t >= off) x = sh[t - off];
            __syncthreads();
            if (t >= off) sh[t] += x;
            __syncthreads();
        }
        if (i < n) {
            int e = carry + sh[t] - v;
            out[i] = e;
            if (oo) oo[i] = e;
        }
        __syncthreads();
        if (t == 255) carry += sh[255];
        __syncthreads();
    }
    if (t == 0) out[n] = carry;
}

__global__ void k_fill_edges(int2* __restrict__ edges, int* __restrict__ off,
                             const int* __restrict__ src, const int* __restrict__ dst,
                             const float* __restrict__ ew, int E) {
    int e = blockIdx.x * 256 + threadIdx.x;
    if (e >= E) return;
    int pos = atomicAdd(&off[dst[e]], 1);
    edges[pos] = make_int2(src[e], __float_as_int(ew[e]));
}

// writes PRE-SHIFTED node ids (i << 7 = byte offset of fp16 row) for pool gathers
__global__ void k_fill_seg2(int* __restrict__ id1, int* __restrict__ o1,
                            const int* __restrict__ b1, const int* __restrict__ l1, int n1_,
                            int* __restrict__ id2, int* __restrict__ o2,
                            const int* __restrict__ b2, const int* __restrict__ l2, int n2_) {
    int i = blockIdx.x * 256 + threadIdx.x;
    if (i < n1_) {
        int pos = atomicAdd(&o1[b1[i] * NROIS + l1[i]], 1);
        id1[pos] = i << 7;
        return;
    }
    int j = i - n1_;
    if (j < n2_) {
        int pos = atomicAdd(&o2[b2[j] * NROIS + l2[j]], 1);
        id2[pos] = j << 7;
    }
}

__global__ void k_deg_dinv(float* __restrict__ dinv, const int* __restrict__ row,
                           const int2* __restrict__ edges, int n) {
    int d = blockIdx.x * 256 + threadIdx.x;
    if (d >= n) return;
    int a = row[d], b = row[d + 1];
    float s = 1.0f;
    for (int i = a; i < b; i++) s += __int_as_float(edges[i].y);
    dinv[d] = rsqrtf(s);
}

// scales weights AND pre-shifts src index to byte offset (src << 7)
__global__ void k_scale(int2* __restrict__ edges, const int* __restrict__ row,
                        const float* __restrict__ dinv, int n) {
    int d = blockIdx.x * 256 + threadIdx.x;
    if (d >= n) return;
    int a = row[d], b = row[d + 1];
    float dd = dinv[d];
    for (int i = a; i < b; i++) {
        int2 e = edges[i];
        edges[i] = make_int2(e.x << 7,
                             __float_as_int(dinv[e.x] * __int_as_float(e.y) * dd));
    }
}

// ---------------- graph-1 radix-partition CSR build ----------------

__global__ __launch_bounds__(256) void k_p1(int* __restrict__ bh, const int* __restrict__ dst) {
    __shared__ int cnt[NB1];
    int t = threadIdx.x, blk = blockIdx.x;
    for (int i = t; i < NB1; i += 256) cnt[i] = 0;
    __syncthreads();
    int base = blk * EPB;
    for (int i = t; i < EPB; i += 256) atomicAdd(&cnt[dst[base + i] >> 8], 1);
    __syncthreads();
    for (int b = t; b < NB1; b += 256) bh[b * BLK1 + blk] = cnt[b];   // bucket-major
}

// pack = src (17 bits) | dst_local (8 bits) << 17
__global__ __launch_bounds__(256) void k_p2(int2* __restrict__ tmp, const int* __restrict__ obh,
                                            const int* __restrict__ src,
                                            const int* __restrict__ dst,
                                            const float* __restrict__ ew) {
    __shared__ int cur[NB1];
    int t = threadIdx.x, blk = blockIdx.x;
    for (int b = t; b < NB1; b += 256) cur[b] = obh[b * BLK1 + blk];
    __syncthreads();
    int base = blk * EPB;
    for (int i = t; i < EPB; i += 256) {
        int e = base + i;
        int d = dst[e];
        int pos = atomicAdd(&cur[d >> 8], 1);
        tmp[pos] = make_int2(src[e] | ((d & 255) << 17), __float_as_int(ew[e]));
    }
}

// per-bucket histogram + weight sums; fused local exclusive scan produces row1
// directly (bucket base = obh[b*BLK1]) -- replaces the 3-dispatch N1 scan chain.
__global__ __launch_bounds__(256) void k_p3a(int* __restrict__ row1, float* __restrict__ dinv,
                                             const int2* __restrict__ tmp,
                                             const int* __restrict__ obh) {
    __shared__ int h[NPB];
    __shared__ float ws[NPB];
    __shared__ int sc[256];
    int t = threadIdx.x, b = blockIdx.x;
    h[t] = 0; ws[t] = 0.f;                 // NPB == 256 == blockDim
    __syncthreads();
    int ebase = obh[b * BLK1];
    int eend  = (b == NB1 - 1) ? E1 : obh[(b + 1) * BLK1];
    for (int i = ebase + t; i < eend; i += 256) {
        int2 ed = tmp[i];
        int dl = (ed.x >> 17) & 255;
        atomicAdd(&h[dl], 1);
        atomicAdd(&ws[dl], __int_as_float(ed.y));
    }
    __syncthreads();
    int cnt = h[t];
    sc[t] = cnt; __syncthreads();
    for (int off = 1; off < 256; off <<= 1) {
        int x = 0; if (t >= off) x = sc[t - off];
        __syncthreads();
        if (t >= off) sc[t] += x;
        __syncthreads();
    }
    row1[b * NPB + t] = ebase + sc[t] - cnt;
    dinv[b * NPB + t] = rsqrtf(1.f + ws[t]);
    if (b == NB1 - 1 && t == 255) row1[N1] = E1;
}

// scatter to final CSR; writes PRE-SHIFTED src (byte offset) for conv gathers
__global__ __launch_bounds__(256) void k_p3b(int2* __restrict__ edges,
                                             const int2* __restrict__ tmp,
                                             const int* __restrict__ obh,
                                             const int* __restrict__ row,
                                             const float* __restrict__ dinv) {
    __shared__ int cur[NPB];
    __shared__ float dvl[NPB];
    int t = threadIdx.x, b = blockIdx.x;
    int n0 = b * NPB;
    for (int i = t; i < NPB; i += 256) {
        cur[i] = row[n0 + i];
        dvl[i] = dinv[n0 + i];
    }
    __syncthreads();
    int a  = obh[b * BLK1];
    int e_ = (b == NB1 - 1) ? E1 : obh[(b + 1) * BLK1];
    for (int i = a + t; i < e_; i += 256) {
        int2 ed = tmp[i];
        int dl = (ed.x >> 17) & 255;
        int s = ed.x & 0x1FFFF;
        int pos = atomicAdd(&cur[dl], 1);
        float w = dinv[s] * __int_as_float(ed.y) * dvl[dl];
        edges[pos] = make_int2(s << 7, __float_as_int(w));
    }
}

// ---------------- dense ops ----------------

__device__ __forceinline__ float4 ldx(const float* x, size_t idx) {
    return *(const float4*)(x + idx);
}
__device__ __forceinline__ float4 ldx(const __half* x, size_t idx) {
    uint2 u = *(const uint2*)(x + idx);
    __half2 a = *(__half2*)&u.x, b = *(__half2*)&u.y;
    float2 fa = __half22float2(a), fb = __half22float2(b);
    return make_float4(fa.x, fa.y, fb.x, fb.y);
}

// out_f16[n][64] = x[n][K] @ W[K][64], fused over both graphs by block range.
template <int K, typename T>
__global__ __launch_bounds__(256) void k_gemm(__half* __restrict__ out1, const T* __restrict__ x1,
                                              const float* __restrict__ W1, int n1_,
                                              __half* __restrict__ out2, const T* __restrict__ x2,
                                              const float* __restrict__ W2, int n2_, int split) {
    __shared__ float Wl[32 * 64];       // [kk][col]
    __shared__ float xs[256 * 37];      // [r][kk], stride 37
    int tid = threadIdx.x;
    __half* out; const T* x; const float* W; int n; int row0;
    if ((int)blockIdx.x < split) { out = out1; x = x1; W = W1; n = n1_; row0 = blockIdx.x * 256; }
    else { out = out2; x = x2; W = W2; n = n2_; row0 = (blockIdx.x - split) * 256; }
    int r0 = (tid >> 3) * 8;
    int c0 = (tid & 7) * 8;
    float acc[8][8];
#pragma unroll
    for (int i = 0; i < 8; i++)
#pragma unroll
        for (int j = 0; j < 8; j++) acc[i][j] = 0.f;

    for (int k0 = 0; k0 < K; k0 += 32) {
        __syncthreads();
        {
            const float4* W4 = (const float4*)(W + k0 * 64);
            float4* Wl4 = (float4*)Wl;
#pragma unroll
            for (int i = 0; i < 2; i++) Wl4[tid + i * 256] = W4[tid + i * 256];
        }
#pragma unroll
        for (int i = 0; i < 8; i++) {
            int idx = tid + i * 256;
            int r = idx >> 3, kq = idx & 7;
            float4 v = make_float4(0.f, 0.f, 0.f, 0.f);
            if (row0 + r < n)
                v = ldx(x, (size_t)(row0 + r) * K + k0 + kq * 4);
            xs[r * 37 + kq * 4 + 0] = v.x;
            xs[r * 37 + kq * 4 + 1] = v.y;
            xs[r * 37 + kq * 4 + 2] = v.z;
            xs[r * 37 + kq * 4 + 3] = v.w;
        }
        __syncthreads();
#pragma unroll 2
        for (int kk = 0; kk < 32; kk++) {
            float4 wlo = *(const float4*)(&Wl[kk * 64 + c0]);
            float4 whi = *(const float4*)(&Wl[kk * 64 + c0 + 4]);
            float xf[8];
#pragma unroll
            for (int i = 0; i < 8; i++) xf[i] = xs[(r0 + i) * 37 + kk];
#pragma unroll
            for (int i = 0; i < 8; i++) {
                acc[i][0] += xf[i] * wlo.x; acc[i][1] += xf[i] * wlo.y;
                acc[i][2] += xf[i] * wlo.z; acc[i][3] += xf[i] * wlo.w;
                acc[i][4] += xf[i] * whi.x; acc[i][5] += xf[i] * whi.y;
                acc[i][6] += xf[i] * whi.z; acc[i][7] += xf[i] * whi.w;
            }
        }
    }
#pragma unroll
    for (int i = 0; i < 8; i++) {
        int row = row0 + r0 + i;
        if (row < n) {
            uint4 o;
            o.x = packh2(acc[i][0], acc[i][1]);
            o.y = packh2(acc[i][2], acc[i][3]);
            o.z = packh2(acc[i][4], acc[i][5]);
            o.w = packh2(acc[i][6], acc[i][7]);
            *(uint4*)(out + (size_t)row * 64 + c0) = o;
        }
    }
}

// fused GCN aggregate v5: best-measured structure (round-1: cooperative 64-edge
// window preload + shfl broadcast, 4 slots x 16 lanes) + fma_mix (no unpack) +
// full-window unroll (16 independent uint2 gathers hoistable per window) +
// pre-shifted src byte offsets (no per-gather shift).
__device__ __forceinline__ void conv_core(__half* __restrict__ out, const __half* __restrict__ h,
                                          const int2* __restrict__ edges,
                                          const int* __restrict__ row,
                                          const float* __restrict__ dinv,
                                          const float* __restrict__ bias, int d, int lane) {
    int slot = lane >> 4;         // edge slot 0..3
    int f4 = lane & 15;           // features f4*4 .. f4*4+3
    const char* hb = (const char*)(h + f4 * 4);
    int a = row[d], b = row[d + 1];
    float acc0[4] = {0.f, 0.f, 0.f, 0.f};
    float acc1[4] = {0.f, 0.f, 0.f, 0.f};

    int base = a;
    for (; base + 64 <= b; base += 64) {          // full windows: no masking
        int2 e = edges[base + lane];
        int sv = e.x, wv = e.y;
#pragma unroll
        for (int j = 0; j < 64; j += 8) {
            int   s0 = __shfl(sv, j + slot);
            float w0 = __int_as_float(__shfl(wv, j + slot));
            int   s1 = __shfl(sv, j + 4 + slot);
            float w1 = __int_as_float(__shfl(wv, j + 4 + slot));
            uint2 h0 = *(const uint2*)(hb + (unsigned)s0);
            uint2 h1 = *(const uint2*)(hb + (unsigned)s1);
            fma_lo(acc0[0], h0.x, w0); fma_hi(acc0[1], h0.x, w0);
            fma_lo(acc0[2], h0.y, w0); fma_hi(acc0[3], h0.y, w0);
            fma_lo(acc1[0], h1.x, w1); fma_hi(acc1[1], h1.x, w1);
            fma_lo(acc1[2], h1.y, w1); fma_hi(acc1[3], h1.y, w1);
        }
    }
    if (base < b) {                               // tail window, zero-weight pad
        int m = b - base;
        int sv = 0, wv = 0;
        if (base + lane < b) { int2 e = edges[base + lane]; sv = e.x; wv = e.y; }
        for (int j = 0; j < m; j += 8) {
            int   s0 = __shfl(sv, j + slot);
            float w0 = __int_as_float(__shfl(wv, j + slot));
            int   s1 = __shfl(sv, j + 4 + slot);
            float w1 = __int_as_float(__shfl(wv, j + 4 + slot));
            uint2 h0 = *(const uint2*)(hb + (unsigned)s0);
            uint2 h1 = *(const uint2*)(hb + (unsigned)s1);
            fma_lo(acc0[0], h0.x, w0); fma_hi(acc0[1], h0.x, w0);
            fma_lo(acc0[2], h0.y, w0); fma_hi(acc0[3], h0.y, w0);
            fma_lo(acc1[0], h1.x, w1); fma_hi(acc1[1], h1.x, w1);
            fma_lo(acc1[2], h1.y, w1); fma_hi(acc1[3], h1.y, w1);
        }
    }
    float r0 = acc0[0] + acc1[0];
    float r1 = acc0[1] + acc1[1];
    float r2 = acc0[2] + acc1[2];
    float r3 = acc0[3] + acc1[3];
    r0 += __shfl_xor(r0, 16); r0 += __shfl_xor(r0, 32);
    r1 += __shfl_xor(r1, 16); r1 += __shfl_xor(r1, 32);
    r2 += __shfl_xor(r2, 16); r2 += __shfl_xor(r2, 32);
    r3 += __shfl_xor(r3, 16); r3 += __shfl_xor(r3, 32);
    if (slot == 0) {
        float di = dinv[d];
        float sl = di * di;
        uint2 hd = *(const uint2*)(hb + ((unsigned)d << 7));
        fma_lo(r0, hd.x, sl); fma_hi(r1, hd.x, sl);
        fma_lo(r2, hd.y, sl); fma_hi(r3, hd.y, sl);
        float4 bb = *(const float4*)(bias + f4 * 4);
        r0 = fmaxf(r0 + bb.x, 0.f);
        r1 = fmaxf(r1 + bb.y, 0.f);
        r2 = fmaxf(r2 + bb.z, 0.f);
        r3 = fmaxf(r3 + bb.w, 0.f);
        uint2 ov;
        ov.x = packh2(r0, r1);
        ov.y = packh2(r2, r3);
        *(uint2*)(out + (size_t)d * HID + f4 * 4) = ov;
    }
}

__global__ __launch_bounds__(256) void k_conv(__half* __restrict__ o1, const __half* __restrict__ h1,
                                              const int2* __restrict__ e1, const int* __restrict__ r1,
                                              const float* __restrict__ dv1, const float* __restrict__ bi1,
                                              int n1_, int nb1_,
                                              __half* __restrict__ o2, const __half* __restrict__ h2,
                                              const int2* __restrict__ e2, const int* __restrict__ r2,
                                              const float* __restrict__ dv2, const float* __restrict__ bi2,
                                              int n2_) {
    int blk = blockIdx.x;
    int lane = threadIdx.x & 63;
    int w = threadIdx.x >> 6;
    if (blk < nb1_) {
        int d = blk * 4 + w;
        if (d < n1_) conv_core(o1, h1, e1, r1, dv1, bi1, d, lane);
    } else {
        int d = (blk - nb1_) * 4 + w;
        if (d < n2_) conv_core(o2, h2, e2, r2, dv2, bi2, d, lane);
    }
}

// segment-mean pool: direct nodeid loads (nodeid pre-shifted to byte offsets),
// fma_mix with w=1 valid / w=0 masked, fp16 rows in, fp32 means out.
__device__ __forceinline__ void pool_core(float* __restrict__ emb, const __half* __restrict__ h,
                                          const int* __restrict__ nodeid,
                                          const int* __restrict__ segrow, int s, int lane) {
    int slot = lane >> 4;
    int f4 = lane & 15;
    const char* hb = (const char*)(h + f4 * 4);
    int a = segrow[s], b = segrow[s + 1];
    float acc[4][4];
#pragma unroll
    for (int k = 0; k < 4; k++)
#pragma unroll
        for (int f = 0; f < 4; f++) acc[k][f] = 0.f;

    int i = a;
    for (; i + 16 <= b; i += 16) {
#pragma unroll
        for (int k = 0; k < 4; k++) {
            int q = nodeid[i + 4 * k + slot];
            uint2 hv = *(const uint2*)(hb + (unsigned)q);
            fma_lo(acc[k][0], hv.x, 1.f); fma_hi(acc[k][1], hv.x, 1.f);
            fma_lo(acc[k][2], hv.y, 1.f); fma_hi(acc[k][3], hv.y, 1.f);
        }
    }
    if (i < b) {
#pragma unroll
        for (int k = 0; k < 4; k++) {
            int idx = i + 4 * k + slot;
            int q = nodeid[min(idx, b - 1)];
            float w = (idx < b) ? 1.f : 0.f;
            uint2 hv = *(const uint2*)(hb + (unsigned)q);
            fma_lo(acc[k][0], hv.x, w); fma_hi(acc[k][1], hv.x, w);
            fma_lo(acc[k][2], hv.y, w); fma_hi(acc[k][3], hv.y, w);
        }
    }
    float r0 = (acc[0][0] + acc[1][0]) + (acc[2][0] + acc[3][0]);
    float r1 = (acc[0][1] + acc[1][1]) + (acc[2][1] + acc[3][1]);
    float r2 = (acc[0][2] + acc[1][2]) + (acc[2][2] + acc[3][2]);
    float r3 = (acc[0][3] + acc[1][3]) + (acc[2][3] + acc[3][3]);
    r0 += __shfl_xor(r0, 16); r0 += __shfl_xor(r0, 32);
    r1 += __shfl_xor(r1, 16); r1 += __shfl_xor(r1, 32);
    r2 += __shfl_xor(r2, 16); r2 += __shfl_xor(r2, 32);
    r3 += __shfl_xor(r3, 16); r3 += __shfl_xor(r3, 32);
    if (slot == 0) {
        float inv = 1.0f / fmaxf((float)(b - a), 1.0f);
        float4 mv = make_float4(r0 * inv, r1 * inv, r2 * inv, r3 * inv);
        *(float4*)(emb + (size_t)s * HID + f4 * 4) = mv;
    }
}

__global__ __launch_bounds__(256) void k_pool(float* __restrict__ em1, const __half* __restrict__ h1,
                                              const int* __restrict__ id1, const int* __restrict__ sr1,
                                              int nbs,
                                              float* __restrict__ em2, const __half* __restrict__ h2,
                                              const int* __restrict__ id2, const int* __restrict__ sr2) {
    int blk = blockIdx.x;
    int lane = threadIdx.x & 63;
    int w = threadIdx.x >> 6;
    if (blk < nbs) {
        int s = blk * 4 + w;
        if (s < NSEG) pool_core(em1, h1, id1, sr1, s, lane);
    } else {
        int s = (blk - nbs) * 4 + w;
        if (s < NSEG) pool_core(em2, h2, id2, sr2, s, lane);
    }
}

// ---------------- classifier ----------------

// computes s = emb1 + emb2 inline; ct==0 blocks also persist esum.
__global__ __launch_bounds__(256) void k_cls(float* __restrict__ part_,
                                             const float* __restrict__ e1,
                                             const float* __restrict__ e2,
                                             float* __restrict__ esum,
                                             const float* __restrict__ Wm1) {
    __shared__ float sl[KCC * 16];      // [kk][b]
    int tid = threadIdx.x;
    int kt = blockIdx.x >> 2, ct = blockIdx.x & 3;
    int k0 = kt * KCC;
    bool wr = (ct == 0);
    for (int i = tid; i < KCC * 16; i += 256) {
        int kk = i & (KCC - 1), b = i >> 7;        // coalesced over kk
        int idx = b * SDIM + k0 + kk;
        float v = e1[idx] + e2[idx];
        sl[kk * 16 + b] = v;
        if (wr) esum[idx] = v;
    }
    __syncthreads();
    int c = ct * 256 + tid;
    bool active = c < CLS;
    float acc[16];
#pragma unroll
    for (int b = 0; b < 16; b++) acc[b] = 0.f;
    const float* wp = Wm1 + (size_t)k0 * CLS + c;
#pragma unroll 2
    for (int kk = 0; kk < KCC; kk++) {
        float w = active ? wp[(size_t)kk * CLS] : 0.f;
        float4 s0 = *(const float4*)(&sl[kk * 16 + 0]);
        float4 s1 = *(const float4*)(&sl[kk * 16 + 4]);
        float4 s2 = *(const float4*)(&sl[kk * 16 + 8]);
        float4 s3 = *(const float4*)(&sl[kk * 16 + 12]);
        acc[0]  += s0.x * w; acc[1]  += s0.y * w; acc[2]  += s0.z * w; acc[3]  += s0.w * w;
        acc[4]  += s1.x * w; acc[5]  += s1.y * w; acc[6]  += s1.z * w; acc[7]  += s1.w * w;
        acc[8]  += s2.x * w; acc[9]  += s2.y * w; acc[10] += s2.z * w; acc[11] += s2.w * w;
        acc[12] += s3.x * w; acc[13] += s3.y * w; acc[14] += s3.z * w; acc[15] += s3.w * w;
    }
    float* pp = part_ + (size_t)(kt * CT1 + ct) * 16 * 256;
#pragma unroll
    for (int b = 0; b < 16; b++) pp[b * 256 + tid] = acc[b];
}

// reduce partials + BatchNorm + LeakyReLU in one pass
__global__ void k_credbn(float* __restrict__ hact, const float* __restrict__ part_,
                         const float* __restrict__ bm1, const float* __restrict__ gamma,
                         const float* __restrict__ beta, const float* __restrict__ mean,
                         const float* __restrict__ var) {
    int idx = blockIdx.x * 256 + threadIdx.x;
    if (idx >= BSZ * CLS) return;
    int b = idx / CLS, c = idx % CLS;
    int ct = c >> 8, cl = c & 255;
    float sum = 0.f;
#pragma unroll 2
    for (int kt = 0; kt < KT1; kt++)
        sum += part_[((size_t)(kt * CT1 + ct) * 16 + b) * 256 + cl];
    float t = sum + bm1[c];
    t = gamma[c] * (t - mean[c]) * rsqrtf(var[c] + 1e-5f) + beta[c];
    hact[idx] = t > 0.f ? t : 0.01f * t;
}

// one block per batch row; 128 partials per output
__global__ void k_out(float* __restrict__ outp, const float* __restrict__ hact,
                      const float* __restrict__ Wm2, const float* __restrict__ bm2) {
    int b = blockIdx.x;
    int tid = threadIdx.x;
    int o = tid & 1, part = tid >> 1;   // 2 outputs x 128 partials
    float acc = (part == 0) ? bm2[o] : 0.f;
    for (int k = part; k < CLS; k += 128) acc += hact[b * CLS + k] * Wm2[k * OCH + o];
    unsafeAtomicAdd(&outp[b * OCH + o], acc);
}

extern "C" void kernel_launch(void* const* d_in, const int* in_sizes, int n_in,
                              void* d_out, int out_size, void* d_ws, size_t ws_size,
                              hipStream_t stream) {
    const float* x1  = (const float*)d_in[0];
    const int*   nl  = (const int*)d_in[1];
    const int*   ei1 = (const int*)d_in[2];
    const float* ew1 = (const float*)d_in[3];
    const int*   ba1 = (const int*)d_in[4];
    const float* x2  = (const float*)d_in[5];
    const int*   rl  = (const int*)d_in[6];
    const int*   ei2 = (const int*)d_in[7];
    const float* ew2 = (const float*)d_in[8];
    const int*   ba2 = (const int*)d_in[9];
    const float* W1a = (const float*)d_in[10];
    const float* b1a = (const float*)d_in[11];
    const float* W1b = (const float*)d_in[12];
    const float* b1b = (const float*)d_in[13];
    const float* W2a = (const float*)d_in[14];
    const float* b2a = (const float*)d_in[15];
    const float* W2b = (const float*)d_in[16];
    const float* b2b = (const float*)d_in[17];
    const float* Wm1 = (const float*)d_in[18];
    const float* bm1 = (const float*)d_in[19];
    const float* gam = (const float*)d_in[20];
    const float* bet = (const float*)d_in[21];
    const float* bmn = (const float*)d_in[22];
    const float* bvr = (const float*)d_in[23];
    const float* Wm2 = (const float*)d_in[24];
    const float* bm2 = (const float*)d_in[25];

    float* out  = (float*)d_out;
    float* emb1 = out + 32;               // embedding        (16 x 9472)
    float* emb2 = emb1 + NSEG * HID;      // embedding_roi
    float* esum = emb2 + NSEG * HID;      // embedding + embedding_roi

    // ---- workspace carve ----
    char* p = (char*)d_ws;
    auto carve = [&](size_t nbytes) { char* q = p; p += (nbytes + 255) & ~(size_t)255; return (void*)q; };
    int*    row1    = (int*)   carve((N1 + 1) * 4);
    int2*   edges1  = (int2*)  carve((size_t)E1 * 8);
    float*  dinv1   = (float*) carve(N1 * 4);
    __half* A1h     = (__half*)carve((size_t)N1 * HID * 2);   // fp16 h (gemm out)
    __half* B1h     = (__half*)carve((size_t)N1 * HID * 2);   // fp16 conv out
    int*    nodeid1 = (int*)   carve(N1 * 4);
    int*    segrow1 = (int*)   carve((NSEG + 1) * 4);
    int*    segoff  = (int*)   carve(2 * NSEG * 4);           // [0..NSEG) g1, [NSEG..) g2
    int*    bh      = (int*)   carve((NB1 * BLK1 + 1) * 4);
    int*    obh     = (int*)   carve((NB1 * BLK1 + 1) * 4);
    int*    row2    = (int*)   carve((N2 + 1) * 4);
    int*    off2    = (int*)   carve(N2 * 4);
    int2*   edges2  = (int2*)  carve((size_t)E2 * 8);
    float*  dinv2   = (float*) carve(N2 * 4);
    __half* A2h     = (__half*)carve((size_t)N2 * HID * 2);
    __half* B2h     = (__half*)carve((size_t)N2 * HID * 2);
    int*    nodeid2 = (int*)   carve(N2 * 4);
    int*    segrow2 = (int*)   carve((NSEG + 1) * 4);
    int*    part    = (int*)   carve(256 * 4);
    float*  hact    = (float*) carve(BSZ * CLS * 4);
    int*    segoff1 = segoff;
    int*    segoff2 = segoff + NSEG;
    int2*  tmp1 = (int2*)B1h;   // 16.8 MB aliases B1h (16.8 MB): CSR build done
                                // before conv1's first B1h write
    float* clsp = (float*)B1h;  // 4.85 MB partial slabs alias B1h: dead after pool

    const int* src1 = ei1;
    const int* dst1 = ei1 + E1;
    const int* src2 = ei2;
    const int* dst2 = ei2 + E2;

    hipMemsetAsync(d_out, 0, (size_t)out_size * sizeof(float), stream);

    // ---------------- graph 2 CSR (small) ----------------
    hipMemsetAsync(off2, 0, N2 * 4, stream);
    k_hist_dst<<<(E2 + 255) / 256, 256, 0, stream>>>(off2, dst2, E2);
    k_scan_one<<<1, 256, 0, stream>>>(off2, row2, off2, N2, nullptr, nullptr, nullptr, 0);
    k_fill_edges<<<(E2 + 255) / 256, 256, 0, stream>>>(edges2, off2, src2, dst2, ew2, E2);
    k_deg_dinv<<<(N2 + 255) / 256, 256, 0, stream>>>(dinv2, row2, edges2, N2);
    k_scale<<<(N2 + 255) / 256, 256, 0, stream>>>(edges2, row2, dinv2, N2);

    // ---------------- graph 1 CSR: radix-partition build ----------------
    k_p1<<<BLK1, 256, 0, stream>>>(bh, dst1);
    k_scan1<<<(NB1 * BLK1 + 1023) / 1024, 256, 0, stream>>>(bh, obh, part, NB1 * BLK1);
    k_scan2<<<1, 256, 0, stream>>>(part, (NB1 * BLK1 + 1023) / 1024);
    k_scan3<<<(NB1 * BLK1 + 255) / 256, 256, 0, stream>>>(obh, part, NB1 * BLK1, E1);
    k_p2<<<BLK1, 256, 0, stream>>>(tmp1, obh, src1, dst1, ew1);
    k_p3a<<<NB1, 256, 0, stream>>>(row1, dinv1, tmp1, obh);      // row1 built in-kernel
    k_p3b<<<NB1, 256, 0, stream>>>(edges1, tmp1, obh, row1, dinv1);

    // ---------------- fused dense pipeline (both graphs per dispatch) ----------------
    k_gemm<INCH, float><<<GB1 + GB2, 256, 0, stream>>>(A1h, x1, W1a, N1, A2h, x2, W2a, N2, GB1);
    k_conv<<<CB1 + CB2, 256, 0, stream>>>(B1h, A1h, edges1, row1, dinv1, b1a, N1, CB1,
                                          B2h, A2h, edges2, row2, dinv2, b2a, N2);
    k_gemm<HID, __half><<<GB1 + GB2, 256, 0, stream>>>(A1h, B1h, W1b, N1, A2h, B2h, W2b, N2, GB1);
    k_conv<<<CB1 + CB2, 256, 0, stream>>>(B1h, A1h, edges1, row1, dinv1, b1b, N1, CB1,
                                          B2h, A2h, edges2, row2, dinv2, b2b, N2);

    // ---------------- segment CSR + pool (both graphs) ----------------
    hipMemsetAsync(segoff, 0, 2 * NSEG * 4, stream);
    k_hist_seg2<<<(N1 + N2 + 255) / 256, 256, 0, stream>>>(segoff1, ba1, nl, N1,
                                                           segoff2, ba2, rl, N2);
    k_scan_one<<<2, 256, 0, stream>>>(segoff1, segrow1, segoff1, NSEG,
                                      segoff2, segrow2, segoff2, NSEG);
    k_fill_seg2<<<(N1 + N2 + 255) / 256, 256, 0, stream>>>(nodeid1, segoff1, ba1, nl, N1,
                                                           nodeid2, segoff2, ba2, rl, N2);
    k_pool<<<PB + PB, 256, 0, stream>>>(emb1, B1h, nodeid1, segrow1, PB,
                                        emb2, B2h, nodeid2, segrow2);
    // B1h dead from here; clsp aliases it

    // ---------------- classifier ----------------
    k_cls<<<KT1 * CT1, 256, 0, stream>>>(clsp, emb1, emb2, esum, Wm1);
    k_credbn<<<(BSZ * CLS + 255) / 256, 256, 0, stream>>>(hact, clsp, bm1, gam, bet, bmn, bvr);
    k_out<<<BSZ, 256, 0, stream>>>(out, hact, Wm2, bm2);
}

// Round 5
// 564.618 us; speedup vs baseline: 1.1255x; 1.0592x over previous
//
#include <hip/hip_runtime.h>
#include <hip/hip_fp16.h>

#define N1 131072
#define E1 2097152
#define N2 2368
#define E2 37888
#define NROIS 148
#define BSZ 16
#define HID 64
#define INCH 128
#define NSEG (BSZ*NROIS)      /* 2368 */
#define SDIM (NROIS*HID)      /* 9472 */
#define CLS 1000
#define OCH 2

#define KT1 74                /* k tiles for k_cls */
#define KCC 128               /* k per tile (74*128 = 9472) */
#define CT1 4                 /* col tiles of 256 */

#define NB1 512               /* dst buckets for graph-1 partition */
#define BLK1 512              /* partition blocks */
#define EPB (E1/BLK1)         /* 4096 edges per block */
#define NPB (N1/NB1)          /* 256 nodes per bucket */

#define CB1 ((N1+3)/4)        /* 32768 conv blocks graph1 */
#define CB2 ((N2+3)/4)        /* 592 conv blocks graph2 */
#define PB  ((NSEG+3)/4)      /* 592 pool blocks per graph */

#define T1 (N1/16)            /* 8192 mfma row-tiles graph1 */
#define T2 (N2/16)            /* 148 mfma row-tiles graph2 */
#define GEMMB ((T1+T2)/4)     /* 2085 gemm blocks (1 tile/wave, 4 waves/block) */

typedef _Float16 h8 __attribute__((ext_vector_type(8)));
typedef float f4 __attribute__((ext_vector_type(4)));

__device__ __forceinline__ unsigned packh2(float a, float b) {
    return (unsigned)__half_as_ushort(__float2half_rn(a)) |
           ((unsigned)__half_as_ushort(__float2half_rn(b)) << 16);
}

// fp32 acc += (f16 half of hb) * w  -- single VALU op, no unpack
__device__ __forceinline__ void fma_lo(float& a, unsigned hb, float w) {
    asm("v_fma_mix_f32 %0, %1, %2, %0 op_sel:[0,0,0] op_sel_hi:[1,0,0]"
        : "+v"(a) : "v"(hb), "v"(w));
}
__device__ __forceinline__ void fma_hi(float& a, unsigned hb, float w) {
    asm("v_fma_mix_f32 %0, %1, %2, %0 op_sel:[1,0,0] op_sel_hi:[1,0,0]"
        : "+v"(a) : "v"(hb), "v"(w));
}

// ---------------- generic small-graph CSR build ----------------

__global__ void k_hist_dst(int* __restrict__ cnt, const int* __restrict__ dst, int E) {
    int e = blockIdx.x * 256 + threadIdx.x;
    if (e < E) atomicAdd(&cnt[dst[e]], 1);
}

__global__ void k_hist_seg2(int* __restrict__ c1, const int* __restrict__ b1,
                            const int* __restrict__ l1, int n1_,
                            int* __restrict__ c2, const int* __restrict__ b2,
                            const int* __restrict__ l2, int n2_) {
    int i = blockIdx.x * 256 + threadIdx.x;
    if (i < n1_) { atomicAdd(&c1[b1[i] * NROIS + l1[i]], 1); return; }
    int j = i - n1_;
    if (j < n2_) atomicAdd(&c2[b2[j] * NROIS + l2[j]], 1);
}

// multi-block exclusive scan (used for the obh bucket histogram)
__global__ void k_scan1(const int* __restrict__ in, int* __restrict__ out,
                        int* __restrict__ part, int n) {
    __shared__ int sh[256];
    int t = threadIdx.x;
    int i0 = blockIdx.x * 1024 + t * 4;
    int v0 = (i0     < n) ? in[i0]     : 0;
    int v1 = (i0 + 1 < n) ? in[i0 + 1] : 0;
    int v2 = (i0 + 2 < n) ? in[i0 + 2] : 0;
    int v3 = (i0 + 3 < n) ? in[i0 + 3] : 0;
    int tot = v0 + v1 + v2 + v3;
    sh[t] = tot; __syncthreads();
    for (int off = 1; off < 256; off <<= 1) {
        int x = 0; if (t >= off) x = sh[t - off];
        __syncthreads();
        if (t >= off) sh[t] += x;
        __syncthreads();
    }
    int excl = sh[t] - tot;
    if (t == 255) part[blockIdx.x] = sh[255];
    if (i0     < n) out[i0]     = excl;
    if (i0 + 1 < n) out[i0 + 1] = excl + v0;
    if (i0 + 2 < n) out[i0 + 2] = excl + v0 + v1;
    if (i0 + 3 < n) out[i0 + 3] = excl + v0 + v1 + v2;
}

__global__ void k_scan2(int* __restrict__ part, int cnt) {
    __shared__ int sh[256];
    int t = threadIdx.x;
    int v = (t < cnt) ? part[t] : 0;
    sh[t] = v; __syncthreads();
    for (int off = 1; off < 256; off <<= 1) {
        int x = 0; if (t >= off) x = sh[t - off];
        __syncthreads();
        if (t >= off) sh[t] += x;
        __syncthreads();
    }
    if (t < cnt) part[t] = sh[t] - v;
}

__global__ void k_scan3(int* __restrict__ out, const int* __restrict__ part, int n, int total) {
    int i = blockIdx.x * 256 + threadIdx.x;
    if (i < n) out[i] += part[i >> 10];
    if (i == 0) out[n] = total;
}

// single-block exclusive scan; block 0 scans set A, block 1 (if in1 != null) set B.
__global__ void k_scan_one(const int* __restrict__ in0, int* __restrict__ out0,
                           int* __restrict__ oo0, int n0,
                           const int* __restrict__ in1, int* __restrict__ out1,
                           int* __restrict__ oo1, int n1_) {
    __shared__ int sh[256];
    __shared__ int carry;
    const int* in; int* out; int* oo; int n;
    if (blockIdx.x == 0) { in = in0; out = out0; oo = oo0; n = n0; }
    else { if (!in1) return; in = in1; out = out1; oo = oo1; n = n1_; }
    int t = threadIdx.x;
    if (t == 0) carry = 0;
    __syncthreads();
    for (int base = 0; base < n; base += 256) {
        int i = base + t;
        int v = (i < n) ? in[i] : 0;
        sh[t] = v; __syncthreads();
        for (int off = 1; off < 256; off <<= 1) {
            int x = 0; if (t >= off) x = sh[t - off];
            __syncthreads();
            if (t >= off) sh[t] += x;
            __syncthreads();
        }
        if (i < n) {
            int e = carry + sh[t] - v;
            out[i] = e;
            if (oo) oo[i] = e;
        }
        __syncthreads();
        if (t == 255) carry += sh[255];
        __syncthreads();
    }
    if (t == 0) out[n] = carry;
}

__global__ void k_fill_edges(int2* __restrict__ edges, int* __restrict__ off,
                             const int* __restrict__ src, const int* __restrict__ dst,
                             const float* __restrict__ ew, int E) {
    int e = blockIdx.x * 256 + threadIdx.x;
    if (e >= E) return;
    int pos = atomicAdd(&off[dst[e]], 1);
    edges[pos] = make_int2(src[e], __float_as_int(ew[e]));
}

// writes PRE-SHIFTED node ids (i << 7 = byte offset of fp16 row) for pool gathers
__global__ void k_fill_seg2(int* __restrict__ id1, int* __restrict__ o1,
                            const int* __restrict__ b1, const int* __restrict__ l1, int n1_,
                            int* __restrict__ id2, int* __restrict__ o2,
                            const int* __restrict__ b2, const int* __restrict__ l2, int n2_) {
    int i = blockIdx.x * 256 + threadIdx.x;
    if (i < n1_) {
        int pos = atomicAdd(&o1[b1[i] * NROIS + l1[i]], 1);
        id1[pos] = i << 7;
        return;
    }
    int j = i - n1_;
    if (j < n2_) {
        int pos = atomicAdd(&o2[b2[j] * NROIS + l2[j]], 1);
        id2[pos] = j << 7;
    }
}

__global__ void k_deg_dinv(float* __restrict__ dinv, const int* __restrict__ row,
                           const int2* __restrict__ edges, int n) {
    int d = blockIdx.x * 256 + threadIdx.x;
    if (d >= n) return;
    int a = row[d], b = row[d + 1];
    float s = 1.0f;
    for (int i = a; i < b; i++) s += __int_as_float(edges[i].y);
    dinv[d] = rsqrtf(s);
}

// scales weights AND pre-shifts src index to byte offset (src << 7)
__global__ void k_scale(int2* __restrict__ edges, const int* __restrict__ row,
                        const float* __restrict__ dinv, int n) {
    int d = blockIdx.x * 256 + threadIdx.x;
    if (d >= n) return;
    int a = row[d], b = row[d + 1];
    float dd = dinv[d];
    for (int i = a; i < b; i++) {
        int2 e = edges[i];
        edges[i] = make_int2(e.x << 7,
                             __float_as_int(dinv[e.x] * __int_as_float(e.y) * dd));
    }
}

// ---------------- graph-1 radix-partition CSR build ----------------

__global__ __launch_bounds__(256) void k_p1(int* __restrict__ bh, const int* __restrict__ dst) {
    __shared__ int cnt[NB1];
    int t = threadIdx.x, blk = blockIdx.x;
    for (int i = t; i < NB1; i += 256) cnt[i] = 0;
    __syncthreads();
    int base = blk * EPB;
    for (int i = t; i < EPB; i += 256) atomicAdd(&cnt[dst[base + i] >> 8], 1);
    __syncthreads();
    for (int b = t; b < NB1; b += 256) bh[b * BLK1 + blk] = cnt[b];   // bucket-major
}

// pack = src (17 bits) | dst_local (8 bits) << 17
__global__ __launch_bounds__(256) void k_p2(int2* __restrict__ tmp, const int* __restrict__ obh,
                                            const int* __restrict__ src,
                                            const int* __restrict__ dst,
                                            const float* __restrict__ ew) {
    __shared__ int cur[NB1];
    int t = threadIdx.x, blk = blockIdx.x;
    for (int b = t; b < NB1; b += 256) cur[b] = obh[b * BLK1 + blk];
    __syncthreads();
    int base = blk * EPB;
    for (int i = t; i < EPB; i += 256) {
        int e = base + i;
        int d = dst[e];
        int pos = atomicAdd(&cur[d >> 8], 1);
        tmp[pos] = make_int2(src[e] | ((d & 255) << 17), __float_as_int(ew[e]));
    }
}

// per-bucket histogram + weight sums; fused local exclusive scan produces row1
__global__ __launch_bounds__(256) void k_p3a(int* __restrict__ row1, float* __restrict__ dinv,
                                             const int2* __restrict__ tmp,
                                             const int* __restrict__ obh) {
    __shared__ int h[NPB];
    __shared__ float ws[NPB];
    __shared__ int sc[256];
    int t = threadIdx.x, b = blockIdx.x;
    h[t] = 0; ws[t] = 0.f;                 // NPB == 256 == blockDim
    __syncthreads();
    int ebase = obh[b * BLK1];
    int eend  = (b == NB1 - 1) ? E1 : obh[(b + 1) * BLK1];
    for (int i = ebase + t; i < eend; i += 256) {
        int2 ed = tmp[i];
        int dl = (ed.x >> 17) & 255;
        atomicAdd(&h[dl], 1);
        atomicAdd(&ws[dl], __int_as_float(ed.y));
    }
    __syncthreads();
    int cnt = h[t];
    sc[t] = cnt; __syncthreads();
    for (int off = 1; off < 256; off <<= 1) {
        int x = 0; if (t >= off) x = sc[t - off];
        __syncthreads();
        if (t >= off) sc[t] += x;
        __syncthreads();
    }
    row1[b * NPB + t] = ebase + sc[t] - cnt;
    dinv[b * NPB + t] = rsqrtf(1.f + ws[t]);
    if (b == NB1 - 1 && t == 255) row1[N1] = E1;
}

// scatter to final CSR; writes PRE-SHIFTED src (byte offset) for conv gathers
__global__ __launch_bounds__(256) void k_p3b(int2* __restrict__ edges,
                                             const int2* __restrict__ tmp,
                                             const int* __restrict__ obh,
                                             const int* __restrict__ row,
                                             const float* __restrict__ dinv) {
    __shared__ int cur[NPB];
    __shared__ float dvl[NPB];
    int t = threadIdx.x, b = blockIdx.x;
    int n0 = b * NPB;
    for (int i = t; i < NPB; i += 256) {
        cur[i] = row[n0 + i];
        dvl[i] = dinv[n0 + i];
    }
    __syncthreads();
    int a  = obh[b * BLK1];
    int e_ = (b == NB1 - 1) ? E1 : obh[(b + 1) * BLK1];
    for (int i = a + t; i < e_; i += 256) {
        int2 ed = tmp[i];
        int dl = (ed.x >> 17) & 255;
        int s = ed.x & 0x1FFFF;
        int pos = atomicAdd(&cur[dl], 1);
        float w = dinv[s] * __int_as_float(ed.y) * dvl[dl];
        edges[pos] = make_int2(s << 7, __float_as_int(w));
    }
}

// ---------------- MFMA gemm ----------------
// out[n][64] = x[n][K] @ W[K][64] via v_mfma_f32_16x16x32_f16.
// Per wave: one 16-row tile, 4 col-tile accumulators. W pre-packed to fragment
// layout fp16 (k_wprep). A and B use the SAME k-permutation within each 32-k
// chunk, so the contraction is correct for any bijective hardware k-mapping.

// W fragment: half j of lane l for (coltile ct, kchunk ch) =
//   W[ch*32 + (l>>4)*8 + j][ct*16 + (l&15)], stored at wf[(ct*KCH+ch)*64 + l]
__device__ __forceinline__ void wfrag(uint4* __restrict__ o, const float* __restrict__ W,
                                      int KCH, int idx) {
    int lane = idx & 63;
    int rest = idx >> 6;
    int ch = rest % KCH;
    int ct = rest / KCH;
    int kr = ch * 32 + ((lane >> 4) * 8);
    int col = ct * 16 + (lane & 15);
    const float* wp = W + (size_t)kr * 64 + col;
    o[idx] = make_uint4(packh2(wp[0],   wp[64]),
                        packh2(wp[128], wp[192]),
                        packh2(wp[256], wp[320]),
                        packh2(wp[384], wp[448]));
}

__global__ void k_wprep(uint4* __restrict__ wf1a, const float* __restrict__ W1a,
                        uint4* __restrict__ wf1b, const float* __restrict__ W1b,
                        uint4* __restrict__ wf2a, const float* __restrict__ W2a,
                        uint4* __restrict__ wf2b, const float* __restrict__ W2b) {
    int idx = blockIdx.x * 256 + threadIdx.x;
    if      (idx < 1024) wfrag(wf1a, W1a, 4, idx);
    else if (idx < 1536) wfrag(wf1b, W1b, 2, idx - 1024);
    else if (idx < 2560) wfrag(wf2a, W2a, 4, idx - 1536);
    else if (idx < 3072) wfrag(wf2b, W2b, 2, idx - 2560);
}

__device__ __forceinline__ h8 loadA(const float* p) {
    float4 a = *(const float4*)p;
    float4 b = *(const float4*)(p + 4);
    union { h8 v; __half h[8]; } u;
    u.h[0] = __float2half_rn(a.x); u.h[1] = __float2half_rn(a.y);
    u.h[2] = __float2half_rn(a.z); u.h[3] = __float2half_rn(a.w);
    u.h[4] = __float2half_rn(b.x); u.h[5] = __float2half_rn(b.y);
    u.h[6] = __float2half_rn(b.z); u.h[7] = __float2half_rn(b.w);
    return u.v;
}
__device__ __forceinline__ h8 loadA(const __half* p) {
    union { h8 v; uint4 u; } u;
    u.u = *(const uint4*)p;
    return u.v;
}

template <int K, typename T>
__global__ __launch_bounds__(256) void k_gemm(__half* __restrict__ out1, const T* __restrict__ x1,
                                              const uint4* __restrict__ wfa, int t1,
                                              __half* __restrict__ out2, const T* __restrict__ x2,
                                              const uint4* __restrict__ wfb, int t2) {
    constexpr int KCH = K / 32;
    int wid = blockIdx.x * 4 + (threadIdx.x >> 6);
    int lane = threadIdx.x & 63;
    __half* out; const T* x; const uint4* wf; int row0;
    if (wid < t1) { out = out1; x = x1; wf = wfa; row0 = wid * 16; }
    else {
        int w2 = wid - t1;
        if (w2 >= t2) return;
        out = out2; x = x2; wf = wfb; row0 = w2 * 16;
    }
    int lrow = lane & 15, lg = lane >> 4;

    h8 bf[4][KCH];
#pragma unroll
    for (int ct = 0; ct < 4; ct++)
#pragma unroll
        for (int ch = 0; ch < KCH; ch++) {
            union { h8 v; uint4 u; } u;
            u.u = wf[(ct * KCH + ch) * 64 + lane];
            bf[ct][ch] = u.v;
        }

    const T* xr = x + (size_t)(row0 + lrow) * K + lg * 8;
    h8 af[KCH];
#pragma unroll
    for (int ch = 0; ch < KCH; ch++) af[ch] = loadA(xr + ch * 32);

    f4 acc[4];
#pragma unroll
    for (int ct = 0; ct < 4; ct++) acc[ct] = (f4){0.f, 0.f, 0.f, 0.f};
#pragma unroll
    for (int ch = 0; ch < KCH; ch++)
#pragma unroll
        for (int ct = 0; ct < 4; ct++)
            acc[ct] = __builtin_amdgcn_mfma_f32_16x16x32_f16(af[ch], bf[ct][ch], acc[ct], 0, 0, 0);

#pragma unroll
    for (int ct = 0; ct < 4; ct++)
#pragma unroll
        for (int r = 0; r < 4; r++)
            out[(size_t)(row0 + lg * 4 + r) * 64 + ct * 16 + lrow] = __float2half_rn(acc[ct][r]);
}

// ---------------- conv / pool ----------------

// fused GCN aggregate: cooperative 64-edge window preload + shfl broadcast,
// 4 slots x 16 lanes, fma_mix, full-window unroll, pre-shifted byte offsets.
__device__ __forceinline__ void conv_core(__half* __restrict__ out, const __half* __restrict__ h,
                                          const int2* __restrict__ edges,
                                          const int* __restrict__ row,
                                          const float* __restrict__ dinv,
                                          const float* __restrict__ bias, int d, int lane) {
    int slot = lane >> 4;         // edge slot 0..3
    int f4i = lane & 15;          // features f4i*4 .. f4i*4+3
    const char* hb = (const char*)(h + f4i * 4);
    int a = row[d], b = row[d + 1];
    float acc0[4] = {0.f, 0.f, 0.f, 0.f};
    float acc1[4] = {0.f, 0.f, 0.f, 0.f};

    int base = a;
    for (; base + 64 <= b; base += 64) {          // full windows: no masking
        int2 e = edges[base + lane];
        int sv = e.x, wv = e.y;
#pragma unroll
        for (int j = 0; j < 64; j += 8) {
            int   s0 = __shfl(sv, j + slot);
            float w0 = __int_as_float(__shfl(wv, j + slot));
            int   s1 = __shfl(sv, j + 4 + slot);
            float w1 = __int_as_float(__shfl(wv, j + 4 + slot));
            uint2 h0 = *(const uint2*)(hb + (unsigned)s0);
            uint2 h1 = *(const uint2*)(hb + (unsigned)s1);
            fma_lo(acc0[0], h0.x, w0); fma_hi(acc0[1], h0.x, w0);
            fma_lo(acc0[2], h0.y, w0); fma_hi(acc0[3], h0.y, w0);
            fma_lo(acc1[0], h1.x, w1); fma_hi(acc1[1], h1.x, w1);
            fma_lo(acc1[2], h1.y, w1); fma_hi(acc1[3], h1.y, w1);
        }
    }
    if (base < b) {                               // tail window, zero-weight pad
        int m = b - base;
        int sv = 0, wv = 0;
        if (base + lane < b) { int2 e = edges[base + lane]; sv = e.x; wv = e.y; }
        for (int j = 0; j < m; j += 8) {
            int   s0 = __shfl(sv, j + slot);
            float w0 = __int_as_float(__shfl(wv, j + slot));
            int   s1 = __shfl(sv, j + 4 + slot);
            float w1 = __int_as_float(__shfl(wv, j + 4 + slot));
            uint2 h0 = *(const uint2*)(hb + (unsigned)s0);
            uint2 h1 = *(const uint2*)(hb + (unsigned)s1);
            fma_lo(acc0[0], h0.x, w0); fma_hi(acc0[1], h0.x, w0);
            fma_lo(acc0[2], h0.y, w0); fma_hi(acc0[3], h0.y, w0);
            fma_lo(acc1[0], h1.x, w1); fma_hi(acc1[1], h1.x, w1);
            fma_lo(acc1[2], h1.y, w1); fma_hi(acc1[3], h1.y, w1);
        }
    }
    float r0 = acc0[0] + acc1[0];
    float r1 = acc0[1] + acc1[1];
    float r2 = acc0[2] + acc1[2];
    float r3 = acc0[3] + acc1[3];
    r0 += __shfl_xor(r0, 16); r0 += __shfl_xor(r0, 32);
    r1 += __shfl_xor(r1, 16); r1 += __shfl_xor(r1, 32);
    r2 += __shfl_xor(r2, 16); r2 += __shfl_xor(r2, 32);
    r3 += __shfl_xor(r3, 16); r3 += __shfl_xor(r3, 32);
    if (slot == 0) {
        float di = dinv[d];
        float sl = di * di;
        uint2 hd = *(const uint2*)(hb + ((unsigned)d << 7));
        fma_lo(r0, hd.x, sl); fma_hi(r1, hd.x, sl);
        fma_lo(r2, hd.y, sl); fma_hi(r3, hd.y, sl);
        float4 bb = *(const float4*)(bias + f4i * 4);
        r0 = fmaxf(r0 + bb.x, 0.f);
        r1 = fmaxf(r1 + bb.y, 0.f);
        r2 = fmaxf(r2 + bb.z, 0.f);
        r3 = fmaxf(r3 + bb.w, 0.f);
        uint2 ov;
        ov.x = packh2(r0, r1);
        ov.y = packh2(r2, r3);
        *(uint2*)(out + (size_t)d * HID + f4i * 4) = ov;
    }
}

__global__ __launch_bounds__(256) void k_conv(__half* __restrict__ o1, const __half* __restrict__ h1,
                                              const int2* __restrict__ e1, const int* __restrict__ r1,
                                              const float* __restrict__ dv1, const float* __restrict__ bi1,
                                              int n1_, int nb1_,
                                              __half* __restrict__ o2, const __half* __restrict__ h2,
                                              const int2* __restrict__ e2, const int* __restrict__ r2,
                                              const float* __restrict__ dv2, const float* __restrict__ bi2,
                                              int n2_) {
    int blk = blockIdx.x;
    int lane = threadIdx.x & 63;
    int w = threadIdx.x >> 6;
    if (blk < nb1_) {
        int d = blk * 4 + w;
        if (d < n1_) conv_core(o1, h1, e1, r1, dv1, bi1, d, lane);
    } else {
        int d = (blk - nb1_) * 4 + w;
        if (d < n2_) conv_core(o2, h2, e2, r2, dv2, bi2, d, lane);
    }
}

// segment-mean pool: direct nodeid loads (pre-shifted byte offsets), fma_mix.
__device__ __forceinline__ void pool_core(float* __restrict__ emb, const __half* __restrict__ h,
                                          const int* __restrict__ nodeid,
                                          const int* __restrict__ segrow, int s, int lane) {
    int slot = lane >> 4;
    int f4i = lane & 15;
    const char* hb = (const char*)(h + f4i * 4);
    int a = segrow[s], b = segrow[s + 1];
    float acc[4][4];
#pragma unroll
    for (int k = 0; k < 4; k++)
#pragma unroll
        for (int f = 0; f < 4; f++) acc[k][f] = 0.f;

    int i = a;
    for (; i + 16 <= b; i += 16) {
#pragma unroll
        for (int k = 0; k < 4; k++) {
            int q = nodeid[i + 4 * k + slot];
            uint2 hv = *(const uint2*)(hb + (unsigned)q);
            fma_lo(acc[k][0], hv.x, 1.f); fma_hi(acc[k][1], hv.x, 1.f);
            fma_lo(acc[k][2], hv.y, 1.f); fma_hi(acc[k][3], hv.y, 1.f);
        }
    }
    if (i < b) {
#pragma unroll
        for (int k = 0; k < 4; k++) {
            int idx = i + 4 * k + slot;
            int q = nodeid[min(idx, b - 1)];
            float w = (idx < b) ? 1.f : 0.f;
            uint2 hv = *(const uint2*)(hb + (unsigned)q);
            fma_lo(acc[k][0], hv.x, w); fma_hi(acc[k][1], hv.x, w);
            fma_lo(acc[k][2], hv.y, w); fma_hi(acc[k][3], hv.y, w);
        }
    }
    float r0 = (acc[0][0] + acc[1][0]) + (acc[2][0] + acc[3][0]);
    float r1 = (acc[0][1] + acc[1][1]) + (acc[2][1] + acc[3][1]);
    float r2 = (acc[0][2] + acc[1][2]) + (acc[2][2] + acc[3][2]);
    float r3 = (acc[0][3] + acc[1][3]) + (acc[2][3] + acc[3][3]);
    r0 += __shfl_xor(r0, 16); r0 += __shfl_xor(r0, 32);
    r1 += __shfl_xor(r1, 16); r1 += __shfl_xor(r1, 32);
    r2 += __shfl_xor(r2, 16); r2 += __shfl_xor(r2, 32);
    r3 += __shfl_xor(r3, 16); r3 += __shfl_xor(r3, 32);
    if (slot == 0) {
        float inv = 1.0f / fmaxf((float)(b - a), 1.0f);
        float4 mv = make_float4(r0 * inv, r1 * inv, r2 * inv, r3 * inv);
        *(float4*)(emb + (size_t)s * HID + f4i * 4) = mv;
    }
}

__global__ __launch_bounds__(256) void k_pool(float* __restrict__ em1, const __half* __restrict__ h1,
                                              const int* __restrict__ id1, const int* __restrict__ sr1,
                                              int nbs,
                                              float* __restrict__ em2, const __half* __restrict__ h2,
                                              const int* __restrict__ id2, const int* __restrict__ sr2) {
    int blk = blockIdx.x;
    int lane = threadIdx.x & 63;
    int w = threadIdx.x >> 6;
    if (blk < nbs) {
        int s = blk * 4 + w;
        if (s < NSEG) pool_core(em1, h1, id1, sr1, s, lane);
    } else {
        int s = (blk - nbs) * 4 + w;
        if (s < NSEG) pool_core(em2, h2, id2, sr2, s, lane);
    }
}

// ---------------- classifier ----------------

__global__ __launch_bounds__(256) void k_cls(float* __restrict__ part_,
                                             const float* __restrict__ e1,
                                             const float* __restrict__ e2,
                                             float* __restrict__ esum,
                                             const float* __restrict__ Wm1) {
    __shared__ float sl[KCC * 16];      // [kk][b]
    int tid = threadIdx.x;
    int kt = blockIdx.x >> 2, ct = blockIdx.x & 3;
    int k0 = kt * KCC;
    bool wr = (ct == 0);
    for (int i = tid; i < KCC * 16; i += 256) {
        int kk = i & (KCC - 1), b = i >> 7;        // coalesced over kk
        int idx = b * SDIM + k0 + kk;
        float v = e1[idx] + e2[idx];
        sl[kk * 16 + b] = v;
        if (wr) esum[idx] = v;
    }
    __syncthreads();
    int c = ct * 256 + tid;
    bool active = c < CLS;
    float acc[16];
#pragma unroll
    for (int b = 0; b < 16; b++) acc[b] = 0.f;
    const float* wp = Wm1 + (size_t)k0 * CLS + c;
#pragma unroll 2
    for (int kk = 0; kk < KCC; kk++) {
        float w = active ? wp[(size_t)kk * CLS] : 0.f;
        float4 s0 = *(const float4*)(&sl[kk * 16 + 0]);
        float4 s1 = *(const float4*)(&sl[kk * 16 + 4]);
        float4 s2 = *(const float4*)(&sl[kk * 16 + 8]);
        float4 s3 = *(const float4*)(&sl[kk * 16 + 12]);
        acc[0]  += s0.x * w; acc[1]  += s0.y * w; acc[2]  += s0.z * w; acc[3]  += s0.w * w;
        acc[4]  += s1.x * w; acc[5]  += s1.y * w; acc[6]  += s1.z * w; acc[7]  += s1.w * w;
        acc[8]  += s2.x * w; acc[9]  += s2.y * w; acc[10] += s2.z * w; acc[11] += s2.w * w;
        acc[12] += s3.x * w; acc[13] += s3.y * w; acc[14] += s3.z * w; acc[15] += s3.w * w;
    }
    float* pp = part_ + (size_t)(kt * CT1 + ct) * 16 * 256;
#pragma unroll
    for (int b = 0; b < 16; b++) pp[b * 256 + tid] = acc[b];
}

// reduce partials + BatchNorm + LeakyReLU in one pass
__global__ void k_credbn(float* __restrict__ hact, const float* __restrict__ part_,
                         const float* __restrict__ bm1, const float* __restrict__ gamma,
                         const float* __restrict__ beta, const float* __restrict__ mean,
                         const float* __restrict__ var) {
    int idx = blockIdx.x * 256 + threadIdx.x;
    if (idx >= BSZ * CLS) return;
    int b = idx / CLS, c = idx % CLS;
    int ct = c >> 8, cl = c & 255;
    float sum = 0.f;
#pragma unroll 2
    for (int kt = 0; kt < KT1; kt++)
        sum += part_[((size_t)(kt * CT1 + ct) * 16 + b) * 256 + cl];
    float t = sum + bm1[c];
    t = gamma[c] * (t - mean[c]) * rsqrtf(var[c] + 1e-5f) + beta[c];
    hact[idx] = t > 0.f ? t : 0.01f * t;
}

// one block per batch row; 128 partials per output
__global__ void k_out(float* __restrict__ outp, const float* __restrict__ hact,
                      const float* __restrict__ Wm2, const float* __restrict__ bm2) {
    int b = blockIdx.x;
    int tid = threadIdx.x;
    int o = tid & 1, part = tid >> 1;   // 2 outputs x 128 partials
    float acc = (part == 0) ? bm2[o] : 0.f;
    for (int k = part; k < CLS; k += 128) acc += hact[b * CLS + k] * Wm2[k * OCH + o];
    unsafeAtomicAdd(&outp[b * OCH + o], acc);
}

extern "C" void kernel_launch(void* const* d_in, const int* in_sizes, int n_in,
                              void* d_out, int out_size, void* d_ws, size_t ws_size,
                              hipStream_t stream) {
    const float* x1  = (const float*)d_in[0];
    const int*   nl  = (const int*)d_in[1];
    const int*   ei1 = (const int*)d_in[2];
    const float* ew1 = (const float*)d_in[3];
    const int*   ba1 = (const int*)d_in[4];
    const float* x2  = (const float*)d_in[5];
    const int*   rl  = (const int*)d_in[6];
    const int*   ei2 = (const int*)d_in[7];
    const float* ew2 = (const float*)d_in[8];
    const int*   ba2 = (const int*)d_in[9];
    const float* W1a = (const float*)d_in[10];
    const float* b1a = (const float*)d_in[11];
    const float* W1b = (const float*)d_in[12];
    const float* b1b = (const float*)d_in[13];
    const float* W2a = (const float*)d_in[14];
    const float* b2a = (const float*)d_in[15];
    const float* W2b = (const float*)d_in[16];
    const float* b2b = (const float*)d_in[17];
    const float* Wm1 = (const float*)d_in[18];
    const float* bm1 = (const float*)d_in[19];
    const float* gam = (const float*)d_in[20];
    const float* bet = (const float*)d_in[21];
    const float* bmn = (const float*)d_in[22];
    const float* bvr = (const float*)d_in[23];
    const float* Wm2 = (const float*)d_in[24];
    const float* bm2 = (const float*)d_in[25];

    float* out  = (float*)d_out;
    float* emb1 = out + 32;               // embedding        (16 x 9472)
    float* emb2 = emb1 + NSEG * HID;      // embedding_roi
    float* esum = emb2 + NSEG * HID;      // embedding + embedding_roi

    // ---- workspace carve ----
    char* p = (char*)d_ws;
    auto carve = [&](size_t nbytes) { char* q = p; p += (nbytes + 255) & ~(size_t)255; return (void*)q; };
    int*    row1    = (int*)   carve((N1 + 1) * 4);
    int2*   edges1  = (int2*)  carve((size_t)E1 * 8);
    float*  dinv1   = (float*) carve(N1 * 4);
    __half* A1h     = (__half*)carve((size_t)N1 * HID * 2);   // fp16 h (gemm out)
    __half* B1h     = (__half*)carve((size_t)N1 * HID * 2);   // fp16 conv out
    int*    nodeid1 = (int*)   carve(N1 * 4);
    int*    segrow1 = (int*)   carve((NSEG + 1) * 4);
    int*    segoff  = (int*)   carve(2 * NSEG * 4);           // [0..NSEG) g1, [NSEG..) g2
    int*    bh      = (int*)   carve((NB1 * BLK1 + 1) * 4);
    int*    obh     = (int*)   carve((NB1 * BLK1 + 1) * 4);
    int*    row2    = (int*)   carve((N2 + 1) * 4);
    int*    off2    = (int*)   carve(N2 * 4);
    int2*   edges2  = (int2*)  carve((size_t)E2 * 8);
    float*  dinv2   = (float*) carve(N2 * 4);
    __half* A2h     = (__half*)carve((size_t)N2 * HID * 2);
    __half* B2h     = (__half*)carve((size_t)N2 * HID * 2);
    int*    nodeid2 = (int*)   carve(N2 * 4);
    int*    segrow2 = (int*)   carve((NSEG + 1) * 4);
    int*    part    = (int*)   carve(256 * 4);
    float*  hact    = (float*) carve(BSZ * CLS * 4);
    uint4*  wf1a    = (uint4*) carve(1024 * 16);              // W fragment buffers
    uint4*  wf1b    = (uint4*) carve(512 * 16);
    uint4*  wf2a    = (uint4*) carve(1024 * 16);
    uint4*  wf2b    = (uint4*) carve(512 * 16);
    int*    segoff1 = segoff;
    int*    segoff2 = segoff + NSEG;
    int2*  tmp1 = (int2*)B1h;   // 16.8 MB aliases B1h (16.8 MB): CSR build done
                                // before conv1's first B1h write
    float* clsp = (float*)B1h;  // 4.85 MB partial slabs alias B1h: dead after pool

    const int* src1 = ei1;
    const int* dst1 = ei1 + E1;
    const int* src2 = ei2;
    const int* dst2 = ei2 + E2;

    hipMemsetAsync(d_out, 0, (size_t)out_size * sizeof(float), stream);

    // ---------------- weight fragment prep (independent; overlaps CSR build) ----
    k_wprep<<<12, 256, 0, stream>>>(wf1a, W1a, wf1b, W1b, wf2a, W2a, wf2b, W2b);

    // ---------------- graph 2 CSR (small) ----------------
    hipMemsetAsync(off2, 0, N2 * 4, stream);
    k_hist_dst<<<(E2 + 255) / 256, 256, 0, stream>>>(off2, dst2, E2);
    k_scan_one<<<1, 256, 0, stream>>>(off2, row2, off2, N2, nullptr, nullptr, nullptr, 0);
    k_fill_edges<<<(E2 + 255) / 256, 256, 0, stream>>>(edges2, off2, src2, dst2, ew2, E2);
    k_deg_dinv<<<(N2 + 255) / 256, 256, 0, stream>>>(dinv2, row2, edges2, N2);
    k_scale<<<(N2 + 255) / 256, 256, 0, stream>>>(edges2, row2, dinv2, N2);

    // ---------------- graph 1 CSR: radix-partition build ----------------
    k_p1<<<BLK1, 256, 0, stream>>>(bh, dst1);
    k_scan1<<<(NB1 * BLK1 + 1023) / 1024, 256, 0, stream>>>(bh, obh, part, NB1 * BLK1);
    k_scan2<<<1, 256, 0, stream>>>(part, (NB1 * BLK1 + 1023) / 1024);
    k_scan3<<<(NB1 * BLK1 + 255) / 256, 256, 0, stream>>>(obh, part, NB1 * BLK1, E1);
    k_p2<<<BLK1, 256, 0, stream>>>(tmp1, obh, src1, dst1, ew1);
    k_p3a<<<NB1, 256, 0, stream>>>(row1, dinv1, tmp1, obh);      // row1 built in-kernel
    k_p3b<<<NB1, 256, 0, stream>>>(edges1, tmp1, obh, row1, dinv1);

    // ---------------- fused dense pipeline (both graphs per dispatch) ----------------
    k_gemm<INCH, float><<<GEMMB, 256, 0, stream>>>(A1h, x1, wf1a, T1, A2h, x2, wf2a, T2);
    k_conv<<<CB1 + CB2, 256, 0, stream>>>(B1h, A1h, edges1, row1, dinv1, b1a, N1, CB1,
                                          B2h, A2h, edges2, row2, dinv2, b2a, N2);
    k_gemm<HID, __half><<<GEMMB, 256, 0, stream>>>(A1h, B1h, wf1b, T1, A2h, B2h, wf2b, T2);
    k_conv<<<CB1 + CB2, 256, 0, stream>>>(B1h, A1h, edges1, row1, dinv1, b1b, N1, CB1,
                                          B2h, A2h, edges2, row2, dinv2, b2b, N2);

    // ---------------- segment CSR + pool (both graphs) ----------------
    hipMemsetAsync(segoff, 0, 2 * NSEG * 4, stream);
    k_hist_seg2<<<(N1 + N2 + 255) / 256, 256, 0, stream>>>(segoff1, ba1, nl, N1,
                                                           segoff2, ba2, rl, N2);
    k_scan_one<<<2, 256, 0, stream>>>(segoff1, segrow1, segoff1, NSEG,
                                      segoff2, segrow2, segoff2, NSEG);
    k_fill_seg2<<<(N1 + N2 + 255) / 256, 256, 0, stream>>>(nodeid1, segoff1, ba1, nl, N1,
                                                           nodeid2, segoff2, ba2, rl, N2);
    k_pool<<<PB + PB, 256, 0, stream>>>(emb1, B1h, nodeid1, segrow1, PB,
                                        emb2, B2h, nodeid2, segrow2);
    // B1h dead from here; clsp aliases it

    // ---------------- classifier ----------------
    k_cls<<<KT1 * CT1, 256, 0, stream>>>(clsp, emb1, emb2, esum, Wm1);
    k_credbn<<<(BSZ * CLS + 255) / 256, 256, 0, stream>>>(hact, clsp, bm1, gam, bet, bmn, bvr);
    k_out<<<BSZ, 256, 0, stream>>>(out, hact, Wm2, bm2);
}

// Round 6
// 556.417 us; speedup vs baseline: 1.1420x; 1.0147x over previous
//
#include <hip/hip_runtime.h>
#include <hip/hip_fp16.h>

#define N1 131072
#define E1 2097152
#define N2 2368
#define E2 37888
#define NROIS 148
#define BSZ 16
#define HID 64
#define INCH 128
#define NSEG (BSZ*NROIS)      /* 2368 */
#define SDIM (NROIS*HID)      /* 9472 */
#define CLS 1000
#define OCH 2

#define KT1 74                /* k tiles for k_cls */
#define KCC 128               /* k per tile (74*128 = 9472) */
#define CT1 4                 /* col tiles of 256 */

#define NB1 512               /* dst buckets for graph-1 partition */
#define BLK1 512              /* partition blocks */
#define EPB (E1/BLK1)         /* 4096 edges per block */
#define NPB (N1/NB1)          /* 256 nodes per bucket */

#define CW1 ((N1+15)/16)      /* 8192 conv blocks graph1 (16 nodes/block) */
#define CW2 ((N2+15)/16)      /* 148 conv blocks graph2 */
#define PW  ((NSEG+15)/16)    /* 148 pool blocks per graph */

#define T1 (N1/16)            /* 8192 mfma row-tiles graph1 */
#define T2 (N2/16)            /* 148 mfma row-tiles graph2 */
#define GEMMB ((T1+T2)/4)     /* 2085 gemm blocks (1 tile/wave, 4 waves/block) */

typedef _Float16 h8 __attribute__((ext_vector_type(8)));
typedef float f4 __attribute__((ext_vector_type(4)));

__device__ __forceinline__ unsigned packh2(float a, float b) {
    return (unsigned)__half_as_ushort(__float2half_rn(a)) |
           ((unsigned)__half_as_ushort(__float2half_rn(b)) << 16);
}

// fp32 acc += (f16 half of hb) * w  -- single VALU op, no unpack
__device__ __forceinline__ void fma_lo(float& a, unsigned hb, float w) {
    asm("v_fma_mix_f32 %0, %1, %2, %0 op_sel:[0,0,0] op_sel_hi:[1,0,0]"
        : "+v"(a) : "v"(hb), "v"(w));
}
__device__ __forceinline__ void fma_hi(float& a, unsigned hb, float w) {
    asm("v_fma_mix_f32 %0, %1, %2, %0 op_sel:[1,0,0] op_sel_hi:[1,0,0]"
        : "+v"(a) : "v"(hb), "v"(w));
}

// ---------------- generic small-graph CSR build ----------------

__global__ void k_hist_dst(int* __restrict__ cnt, const int* __restrict__ dst, int E) {
    int e = blockIdx.x * 256 + threadIdx.x;
    if (e < E) atomicAdd(&cnt[dst[e]], 1);
}

__global__ void k_hist_seg2(int* __restrict__ c1, const int* __restrict__ b1,
                            const int* __restrict__ l1, int n1_,
                            int* __restrict__ c2, const int* __restrict__ b2,
                            const int* __restrict__ l2, int n2_) {
    int i = blockIdx.x * 256 + threadIdx.x;
    if (i < n1_) { atomicAdd(&c1[b1[i] * NROIS + l1[i]], 1); return; }
    int j = i - n1_;
    if (j < n2_) atomicAdd(&c2[b2[j] * NROIS + l2[j]], 1);
}

// multi-block exclusive scan (used for the obh bucket histogram)
__global__ void k_scan1(const int* __restrict__ in, int* __restrict__ out,
                        int* __restrict__ part, int n) {
    __shared__ int sh[256];
    int t = threadIdx.x;
    int i0 = blockIdx.x * 1024 + t * 4;
    int v0 = (i0     < n) ? in[i0]     : 0;
    int v1 = (i0 + 1 < n) ? in[i0 + 1] : 0;
    int v2 = (i0 + 2 < n) ? in[i0 + 2] : 0;
    int v3 = (i0 + 3 < n) ? in[i0 + 3] : 0;
    int tot = v0 + v1 + v2 + v3;
    sh[t] = tot; __syncthreads();
    for (int off = 1; off < 256; off <<= 1) {
        int x = 0; if (t >= off) x = sh[t - off];
        __syncthreads();
        if (t >= off) sh[t] += x;
        __syncthreads();
    }
    int excl = sh[t] - tot;
    if (t == 255) part[blockIdx.x] = sh[255];
    if (i0     < n) out[i0]     = excl;
    if (i0 + 1 < n) out[i0 + 1] = excl + v0;
    if (i0 + 2 < n) out[i0 + 2] = excl + v0 + v1;
    if (i0 + 3 < n) out[i0 + 3] = excl + v0 + v1 + v2;
}

__global__ void k_scan2(int* __restrict__ part, int cnt) {
    __shared__ int sh[256];
    int t = threadIdx.x;
    int v = (t < cnt) ? part[t] : 0;
    sh[t] = v; __syncthreads();
    for (int off = 1; off < 256; off <<= 1) {
        int x = 0; if (t >= off) x = sh[t - off];
        __syncthreads();
        if (t >= off) sh[t] += x;
        __syncthreads();
    }
    if (t < cnt) part[t] = sh[t] - v;
}

__global__ void k_scan3(int* __restrict__ out, const int* __restrict__ part, int n, int total) {
    int i = blockIdx.x * 256 + threadIdx.x;
    if (i < n) out[i] += part[i >> 10];
    if (i == 0) out[n] = total;
}

// single-block exclusive scan; block 0 scans set A, block 1 (if in1 != null) set B.
__global__ void k_scan_one(const int* __restrict__ in0, int* __restrict__ out0,
                           int* __restrict__ oo0, int n0,
                           const int* __restrict__ in1, int* __restrict__ out1,
                           int* __restrict__ oo1, int n1_) {
    __shared__ int sh[256];
    __shared__ int carry;
    const int* in; int* out; int* oo; int n;
    if (blockIdx.x == 0) { in = in0; out = out0; oo = oo0; n = n0; }
    else { if (!in1) return; in = in1; out = out1; oo = oo1; n = n1_; }
    int t = threadIdx.x;
    if (t == 0) carry = 0;
    __syncthreads();
    for (int base = 0; base < n; base += 256) {
        int i = base + t;
        int v = (i < n) ? in[i] : 0;
        sh[t] = v; __syncthreads();
        for (int off = 1; off < 256; off <<= 1) {
            int x = 0; if (t >= off) x = sh[t - off];
            __syncthreads();
            if (t >= off) sh[t] += x;
            __syncthreads();
        }
        if (i < n) {
            int e = carry + sh[t] - v;
            out[i] = e;
            if (oo) oo[i] = e;
        }
        __syncthreads();
        if (t == 255) carry += sh[255];
        __syncthreads();
    }
    if (t == 0) out[n] = carry;
}

__global__ void k_fill_edges(int2* __restrict__ edges, int* __restrict__ off,
                             const int* __restrict__ src, const int* __restrict__ dst,
                             const float* __restrict__ ew, int E) {
    int e = blockIdx.x * 256 + threadIdx.x;
    if (e >= E) return;
    int pos = atomicAdd(&off[dst[e]], 1);
    edges[pos] = make_int2(src[e], __float_as_int(ew[e]));
}

// writes PRE-SHIFTED node ids (i << 7 = byte offset of fp16 row) for pool gathers
__global__ void k_fill_seg2(int* __restrict__ id1, int* __restrict__ o1,
                            const int* __restrict__ b1, const int* __restrict__ l1, int n1_,
                            int* __restrict__ id2, int* __restrict__ o2,
                            const int* __restrict__ b2, const int* __restrict__ l2, int n2_) {
    int i = blockIdx.x * 256 + threadIdx.x;
    if (i < n1_) {
        int pos = atomicAdd(&o1[b1[i] * NROIS + l1[i]], 1);
        id1[pos] = i << 7;
        return;
    }
    int j = i - n1_;
    if (j < n2_) {
        int pos = atomicAdd(&o2[b2[j] * NROIS + l2[j]], 1);
        id2[pos] = j << 7;
    }
}

__global__ void k_deg_dinv(float* __restrict__ dinv, const int* __restrict__ row,
                           const int2* __restrict__ edges, int n) {
    int d = blockIdx.x * 256 + threadIdx.x;
    if (d >= n) return;
    int a = row[d], b = row[d + 1];
    float s = 1.0f;
    for (int i = a; i < b; i++) s += __int_as_float(edges[i].y);
    dinv[d] = rsqrtf(s);
}

// scales weights AND pre-shifts src index to byte offset (src << 7)
__global__ void k_scale(int2* __restrict__ edges, const int* __restrict__ row,
                        const float* __restrict__ dinv, int n) {
    int d = blockIdx.x * 256 + threadIdx.x;
    if (d >= n) return;
    int a = row[d], b = row[d + 1];
    float dd = dinv[d];
    for (int i = a; i < b; i++) {
        int2 e = edges[i];
        edges[i] = make_int2(e.x << 7,
                             __float_as_int(dinv[e.x] * __int_as_float(e.y) * dd));
    }
}

// ---------------- graph-1 radix-partition CSR build ----------------

__global__ __launch_bounds__(256) void k_p1(int* __restrict__ bh, const int* __restrict__ dst) {
    __shared__ int cnt[NB1];
    int t = threadIdx.x, blk = blockIdx.x;
    for (int i = t; i < NB1; i += 256) cnt[i] = 0;
    __syncthreads();
    int base = blk * EPB;
    for (int i = t; i < EPB; i += 256) atomicAdd(&cnt[dst[base + i] >> 8], 1);
    __syncthreads();
    for (int b = t; b < NB1; b += 256) bh[b * BLK1 + blk] = cnt[b];   // bucket-major
}

// pack = src (17 bits) | dst_local (8 bits) << 17
__global__ __launch_bounds__(256) void k_p2(int2* __restrict__ tmp, const int* __restrict__ obh,
                                            const int* __restrict__ src,
                                            const int* __restrict__ dst,
                                            const float* __restrict__ ew) {
    __shared__ int cur[NB1];
    int t = threadIdx.x, blk = blockIdx.x;
    for (int b = t; b < NB1; b += 256) cur[b] = obh[b * BLK1 + blk];
    __syncthreads();
    int base = blk * EPB;
    for (int i = t; i < EPB; i += 256) {
        int e = base + i;
        int d = dst[e];
        int pos = atomicAdd(&cur[d >> 8], 1);
        tmp[pos] = make_int2(src[e] | ((d & 255) << 17), __float_as_int(ew[e]));
    }
}

// per-bucket histogram + weight sums; fused local exclusive scan produces row1
__global__ __launch_bounds__(256) void k_p3a(int* __restrict__ row1, float* __restrict__ dinv,
                                             const int2* __restrict__ tmp,
                                             const int* __restrict__ obh) {
    __shared__ int h[NPB];
    __shared__ float ws[NPB];
    __shared__ int sc[256];
    int t = threadIdx.x, b = blockIdx.x;
    h[t] = 0; ws[t] = 0.f;                 // NPB == 256 == blockDim
    __syncthreads();
    int ebase = obh[b * BLK1];
    int eend  = (b == NB1 - 1) ? E1 : obh[(b + 1) * BLK1];
    for (int i = ebase + t; i < eend; i += 256) {
        int2 ed = tmp[i];
        int dl = (ed.x >> 17) & 255;
        atomicAdd(&h[dl], 1);
        atomicAdd(&ws[dl], __int_as_float(ed.y));
    }
    __syncthreads();
    int cnt = h[t];
    sc[t] = cnt; __syncthreads();
    for (int off = 1; off < 256; off <<= 1) {
        int x = 0; if (t >= off) x = sc[t - off];
        __syncthreads();
        if (t >= off) sc[t] += x;
        __syncthreads();
    }
    row1[b * NPB + t] = ebase + sc[t] - cnt;
    dinv[b * NPB + t] = rsqrtf(1.f + ws[t]);
    if (b == NB1 - 1 && t == 255) row1[N1] = E1;
}

// scatter to final CSR; writes PRE-SHIFTED src (byte offset) for conv gathers
__global__ __launch_bounds__(256) void k_p3b(int2* __restrict__ edges,
                                             const int2* __restrict__ tmp,
                                             const int* __restrict__ obh,
                                             const int* __restrict__ row,
                                             const float* __restrict__ dinv) {
    __shared__ int cur[NPB];
    __shared__ float dvl[NPB];
    int t = threadIdx.x, b = blockIdx.x;
    int n0 = b * NPB;
    for (int i = t; i < NPB; i += 256) {
        cur[i] = row[n0 + i];
        dvl[i] = dinv[n0 + i];
    }
    __syncthreads();
    int a  = obh[b * BLK1];
    int e_ = (b == NB1 - 1) ? E1 : obh[(b + 1) * BLK1];
    for (int i = a + t; i < e_; i += 256) {
        int2 ed = tmp[i];
        int dl = (ed.x >> 17) & 255;
        int s = ed.x & 0x1FFFF;
        int pos = atomicAdd(&cur[dl], 1);
        float w = dinv[s] * __int_as_float(ed.y) * dvl[dl];
        edges[pos] = make_int2(s << 7, __float_as_int(w));
    }
}

// ---------------- MFMA gemm ----------------
// out[n][64] = x[n][K] @ W[K][64] via v_mfma_f32_16x16x32_f16.

__device__ __forceinline__ void wfrag(uint4* __restrict__ o, const float* __restrict__ W,
                                      int KCH, int idx) {
    int lane = idx & 63;
    int rest = idx >> 6;
    int ch = rest % KCH;
    int ct = rest / KCH;
    int kr = ch * 32 + ((lane >> 4) * 8);
    int col = ct * 16 + (lane & 15);
    const float* wp = W + (size_t)kr * 64 + col;
    o[idx] = make_uint4(packh2(wp[0],   wp[64]),
                        packh2(wp[128], wp[192]),
                        packh2(wp[256], wp[320]),
                        packh2(wp[384], wp[448]));
}

__global__ void k_wprep(uint4* __restrict__ wf1a, const float* __restrict__ W1a,
                        uint4* __restrict__ wf1b, const float* __restrict__ W1b,
                        uint4* __restrict__ wf2a, const float* __restrict__ W2a,
                        uint4* __restrict__ wf2b, const float* __restrict__ W2b) {
    int idx = blockIdx.x * 256 + threadIdx.x;
    if      (idx < 1024) wfrag(wf1a, W1a, 4, idx);
    else if (idx < 1536) wfrag(wf1b, W1b, 2, idx - 1024);
    else if (idx < 2560) wfrag(wf2a, W2a, 4, idx - 1536);
    else if (idx < 3072) wfrag(wf2b, W2b, 2, idx - 2560);
}

__device__ __forceinline__ h8 loadA(const float* p) {
    float4 a = *(const float4*)p;
    float4 b = *(const float4*)(p + 4);
    union { h8 v; __half h[8]; } u;
    u.h[0] = __float2half_rn(a.x); u.h[1] = __float2half_rn(a.y);
    u.h[2] = __float2half_rn(a.z); u.h[3] = __float2half_rn(a.w);
    u.h[4] = __float2half_rn(b.x); u.h[5] = __float2half_rn(b.y);
    u.h[6] = __float2half_rn(b.z); u.h[7] = __float2half_rn(b.w);
    return u.v;
}
__device__ __forceinline__ h8 loadA(const __half* p) {
    union { h8 v; uint4 u; } u;
    u.u = *(const uint4*)p;
    return u.v;
}

template <int K, typename T>
__global__ __launch_bounds__(256) void k_gemm(__half* __restrict__ out1, const T* __restrict__ x1,
                                              const uint4* __restrict__ wfa, int t1,
                                              __half* __restrict__ out2, const T* __restrict__ x2,
                                              const uint4* __restrict__ wfb, int t2) {
    constexpr int KCH = K / 32;
    int wid = blockIdx.x * 4 + (threadIdx.x >> 6);
    int lane = threadIdx.x & 63;
    __half* out; const T* x; const uint4* wf; int row0;
    if (wid < t1) { out = out1; x = x1; wf = wfa; row0 = wid * 16; }
    else {
        int w2 = wid - t1;
        if (w2 >= t2) return;
        out = out2; x = x2; wf = wfb; row0 = w2 * 16;
    }
    int lrow = lane & 15, lg = lane >> 4;

    h8 bf[4][KCH];
#pragma unroll
    for (int ct = 0; ct < 4; ct++)
#pragma unroll
        for (int ch = 0; ch < KCH; ch++) {
            union { h8 v; uint4 u; } u;
            u.u = wf[(ct * KCH + ch) * 64 + lane];
            bf[ct][ch] = u.v;
        }

    const T* xr = x + (size_t)(row0 + lrow) * K + lg * 8;
    h8 af[KCH];
#pragma unroll
    for (int ch = 0; ch < KCH; ch++) af[ch] = loadA(xr + ch * 32);

    f4 acc[4];
#pragma unroll
    for (int ct = 0; ct < 4; ct++) acc[ct] = (f4){0.f, 0.f, 0.f, 0.f};
#pragma unroll
    for (int ch = 0; ch < KCH; ch++)
#pragma unroll
        for (int ct = 0; ct < 4; ct++)
            acc[ct] = __builtin_amdgcn_mfma_f32_16x16x32_f16(af[ch], bf[ct][ch], acc[ct], 0, 0, 0);

#pragma unroll
    for (int ct = 0; ct < 4; ct++)
#pragma unroll
        for (int r = 0; r < 4; r++)
            out[(size_t)(row0 + lg * 4 + r) * 64 + ct * 16 + lrow] = __float2half_rn(acc[ct][r]);
}

// ---------------- conv / pool (v6: 4 nodes/wave, 16 lanes/node, uint4 gathers) ----------------
// Group of 16 lanes owns one dst node: lane covers 8 features (uint4 = 16 B),
// 8 lanes span the 128-B row, so the group processes 2 edges per step and one
// wave-wide gather fetches 8 rows (1 KB). No cross-slot butterfly (one
// shfl_xor(8) fold). 4 independent per-group chains overlap inside the wave.
__device__ __forceinline__ void conv_wave(__half* __restrict__ out, const __half* __restrict__ h,
                                          const int2* __restrict__ edges,
                                          const int* __restrict__ row,
                                          const float* __restrict__ dinv,
                                          const float* __restrict__ bias,
                                          int d0, int n, int lane) {
    int g  = lane >> 4;           // node slot 0..3
    int fl = lane & 15;
    int eh = fl >> 3;             // edge half 0/1
    int f8 = fl & 7;              // feature octet: features f8*8 .. f8*8+7
    int d  = d0 + g;
    bool vn = d < n;
    int a = 0, b = 0;
    if (vn) { a = row[d]; b = row[d + 1]; }
    const char* hb = (const char*)h + f8 * 16;
    float acc[8] = {0.f,0.f,0.f,0.f,0.f,0.f,0.f,0.f};

    for (int base = a; base < b; base += 16) {
        int sv = 0, wv = 0;       // zero-pad: w=0 kills invalid contributions
        if (base + fl < b) { int2 e = edges[base + fl]; sv = e.x; wv = e.y; }
        int mm = b - base; if (mm > 16) mm = 16;
        int steps = (mm + 1) >> 1;
        int idx = (g << 4) + eh;
        for (int t = 0; t < steps; t++) {
            int   s = __shfl(sv, idx + (t << 1));
            float w = __int_as_float(__shfl(wv, idx + (t << 1)));
            uint4 hv = *(const uint4*)(hb + (unsigned)s);
            fma_lo(acc[0], hv.x, w); fma_hi(acc[1], hv.x, w);
            fma_lo(acc[2], hv.y, w); fma_hi(acc[3], hv.y, w);
            fma_lo(acc[4], hv.z, w); fma_hi(acc[5], hv.z, w);
            fma_lo(acc[6], hv.w, w); fma_hi(acc[7], hv.w, w);
        }
    }
    float r[8];
#pragma unroll
    for (int f = 0; f < 8; f++) r[f] = acc[f] + __shfl_xor(acc[f], 8);
    if (vn && eh == 0) {
        float di = dinv[d];
        float sl = di * di;
        uint4 hd = *(const uint4*)(hb + ((unsigned)d << 7));
        fma_lo(r[0], hd.x, sl); fma_hi(r[1], hd.x, sl);
        fma_lo(r[2], hd.y, sl); fma_hi(r[3], hd.y, sl);
        fma_lo(r[4], hd.z, sl); fma_hi(r[5], hd.z, sl);
        fma_lo(r[6], hd.w, sl); fma_hi(r[7], hd.w, sl);
        float4 b0 = *(const float4*)(bias + f8 * 8);
        float4 b1 = *(const float4*)(bias + f8 * 8 + 4);
        uint4 ov;
        ov.x = packh2(fmaxf(r[0] + b0.x, 0.f), fmaxf(r[1] + b0.y, 0.f));
        ov.y = packh2(fmaxf(r[2] + b0.z, 0.f), fmaxf(r[3] + b0.w, 0.f));
        ov.z = packh2(fmaxf(r[4] + b1.x, 0.f), fmaxf(r[5] + b1.y, 0.f));
        ov.w = packh2(fmaxf(r[6] + b1.z, 0.f), fmaxf(r[7] + b1.w, 0.f));
        *(uint4*)(out + (size_t)d * HID + f8 * 8) = ov;
    }
}

__global__ __launch_bounds__(256) void k_conv(__half* __restrict__ o1, const __half* __restrict__ h1,
                                              const int2* __restrict__ e1, const int* __restrict__ r1,
                                              const float* __restrict__ dv1, const float* __restrict__ bi1,
                                              int n1_, int nb1_,
                                              __half* __restrict__ o2, const __half* __restrict__ h2,
                                              const int2* __restrict__ e2, const int* __restrict__ r2,
                                              const float* __restrict__ dv2, const float* __restrict__ bi2,
                                              int n2_) {
    int blk = blockIdx.x;
    int lane = threadIdx.x & 63;
    int wv = threadIdx.x >> 6;
    if (blk < nb1_) conv_wave(o1, h1, e1, r1, dv1, bi1, blk * 16 + wv * 4, n1_, lane);
    else            conv_wave(o2, h2, e2, r2, dv2, bi2, (blk - nb1_) * 16 + wv * 4, n2_, lane);
}

// segment-mean pool, same wave structure (weight 1 / 0-masked).
__device__ __forceinline__ void pool_wave(float* __restrict__ emb, const __half* __restrict__ h,
                                          const int* __restrict__ nodeid,
                                          const int* __restrict__ segrow, int s0, int lane) {
    int g  = lane >> 4;
    int fl = lane & 15;
    int eh = fl >> 3;
    int f8 = fl & 7;
    int s  = s0 + g;
    bool vs = s < NSEG;
    int a = 0, b = 0;
    if (vs) { a = segrow[s]; b = segrow[s + 1]; }
    const char* hb = (const char*)h + f8 * 16;
    float acc[8] = {0.f,0.f,0.f,0.f,0.f,0.f,0.f,0.f};

    for (int base = a; base < b; base += 16) {
        int sv = 0, wv = 0;
        if (base + fl < b) { sv = nodeid[base + fl]; wv = 0x3f800000; }
        int mm = b - base; if (mm > 16) mm = 16;
        int steps = (mm + 1) >> 1;
        int idx = (g << 4) + eh;
        for (int t = 0; t < steps; t++) {
            int   q = __shfl(sv, idx + (t << 1));
            float w = __int_as_float(__shfl(wv, idx + (t << 1)));
            uint4 hv = *(const uint4*)(hb + (unsigned)q);
            fma_lo(acc[0], hv.x, w); fma_hi(acc[1], hv.x, w);
            fma_lo(acc[2], hv.y, w); fma_hi(acc[3], hv.y, w);
            fma_lo(acc[4], hv.z, w); fma_hi(acc[5], hv.z, w);
            fma_lo(acc[6], hv.w, w); fma_hi(acc[7], hv.w, w);
        }
    }
    float r[8];
#pragma unroll
    for (int f = 0; f < 8; f++) r[f] = acc[f] + __shfl_xor(acc[f], 8);
    if (vs && eh == 0) {
        float inv = 1.0f / fmaxf((float)(b - a), 1.0f);
        float4 lo = make_float4(r[0] * inv, r[1] * inv, r[2] * inv, r[3] * inv);
        float4 hi = make_float4(r[4] * inv, r[5] * inv, r[6] * inv, r[7] * inv);
        *(float4*)(emb + (size_t)s * HID + f8 * 8)     = lo;
        *(float4*)(emb + (size_t)s * HID + f8 * 8 + 4) = hi;
    }
}

__global__ __launch_bounds__(256) void k_pool(float* __restrict__ em1, const __half* __restrict__ h1,
                                              const int* __restrict__ id1, const int* __restrict__ sr1,
                                              int nbs,
                                              float* __restrict__ em2, const __half* __restrict__ h2,
                                              const int* __restrict__ id2, const int* __restrict__ sr2) {
    int blk = blockIdx.x;
    int lane = threadIdx.x & 63;
    int wv = threadIdx.x >> 6;
    if (blk < nbs) pool_wave(em1, h1, id1, sr1, blk * 16 + wv * 4, lane);
    else           pool_wave(em2, h2, id2, sr2, (blk - nbs) * 16 + wv * 4, lane);
}

// ---------------- classifier ----------------

__global__ __launch_bounds__(256) void k_cls(float* __restrict__ part_,
                                             const float* __restrict__ e1,
                                             const float* __restrict__ e2,
                                             float* __restrict__ esum,
                                             const float* __restrict__ Wm1) {
    __shared__ float sl[KCC * 16];      // [kk][b]
    int tid = threadIdx.x;
    int kt = blockIdx.x >> 2, ct = blockIdx.x & 3;
    int k0 = kt * KCC;
    bool wr = (ct == 0);
    for (int i = tid; i < KCC * 16; i += 256) {
        int kk = i & (KCC - 1), b = i >> 7;        // coalesced over kk
        int idx = b * SDIM + k0 + kk;
        float v = e1[idx] + e2[idx];
        sl[kk * 16 + b] = v;
        if (wr) esum[idx] = v;
    }
    __syncthreads();
    int c = ct * 256 + tid;
    bool active = c < CLS;
    float acc[16];
#pragma unroll
    for (int b = 0; b < 16; b++) acc[b] = 0.f;
    const float* wp = Wm1 + (size_t)k0 * CLS + c;
#pragma unroll 2
    for (int kk = 0; kk < KCC; kk++) {
        float w = active ? wp[(size_t)kk * CLS] : 0.f;
        float4 s0 = *(const float4*)(&sl[kk * 16 + 0]);
        float4 s1 = *(const float4*)(&sl[kk * 16 + 4]);
        float4 s2 = *(const float4*)(&sl[kk * 16 + 8]);
        float4 s3 = *(const float4*)(&sl[kk * 16 + 12]);
        acc[0]  += s0.x * w; acc[1]  += s0.y * w; acc[2]  += s0.z * w; acc[3]  += s0.w * w;
        acc[4]  += s1.x * w; acc[5]  += s1.y * w; acc[6]  += s1.z * w; acc[7]  += s1.w * w;
        acc[8]  += s2.x * w; acc[9]  += s2.y * w; acc[10] += s2.z * w; acc[11] += s2.w * w;
        acc[12] += s3.x * w; acc[13] += s3.y * w; acc[14] += s3.z * w; acc[15] += s3.w * w;
    }
    float* pp = part_ + (size_t)(kt * CT1 + ct) * 16 * 256;
#pragma unroll
    for (int b = 0; b < 16; b++) pp[b * 256 + tid] = acc[b];
}

// reduce partials + BatchNorm + LeakyReLU in one pass
__global__ void k_credbn(float* __restrict__ hact, const float* __restrict__ part_,
                         const float* __restrict__ bm1, const float* __restrict__ gamma,
                         const float* __restrict__ beta, const float* __restrict__ mean,
                         const float* __restrict__ var) {
    int idx = blockIdx.x * 256 + threadIdx.x;
    if (idx >= BSZ * CLS) return;
    int b = idx / CLS, c = idx % CLS;
    int ct = c >> 8, cl = c & 255;
    float sum = 0.f;
#pragma unroll 2
    for (int kt = 0; kt < KT1; kt++)
        sum += part_[((size_t)(kt * CT1 + ct) * 16 + b) * 256 + cl];
    float t = sum + bm1[c];
    t = gamma[c] * (t - mean[c]) * rsqrtf(var[c] + 1e-5f) + beta[c];
    hact[idx] = t > 0.f ? t : 0.01f * t;
}

// one block per batch row; 128 partials per output
__global__ void k_out(float* __restrict__ outp, const float* __restrict__ hact,
                      const float* __restrict__ Wm2, const float* __restrict__ bm2) {
    int b = blockIdx.x;
    int tid = threadIdx.x;
    int o = tid & 1, part = tid >> 1;   // 2 outputs x 128 partials
    float acc = (part == 0) ? bm2[o] : 0.f;
    for (int k = part; k < CLS; k += 128) acc += hact[b * CLS + k] * Wm2[k * OCH + o];
    unsafeAtomicAdd(&outp[b * OCH + o], acc);
}

extern "C" void kernel_launch(void* const* d_in, const int* in_sizes, int n_in,
                              void* d_out, int out_size, void* d_ws, size_t ws_size,
                              hipStream_t stream) {
    const float* x1  = (const float*)d_in[0];
    const int*   nl  = (const int*)d_in[1];
    const int*   ei1 = (const int*)d_in[2];
    const float* ew1 = (const float*)d_in[3];
    const int*   ba1 = (const int*)d_in[4];
    const float* x2  = (const float*)d_in[5];
    const int*   rl  = (const int*)d_in[6];
    const int*   ei2 = (const int*)d_in[7];
    const float* ew2 = (const float*)d_in[8];
    const int*   ba2 = (const int*)d_in[9];
    const float* W1a = (const float*)d_in[10];
    const float* b1a = (const float*)d_in[11];
    const float* W1b = (const float*)d_in[12];
    const float* b1b = (const float*)d_in[13];
    const float* W2a = (const float*)d_in[14];
    const float* b2a = (const float*)d_in[15];
    const float* W2b = (const float*)d_in[16];
    const float* b2b = (const float*)d_in[17];
    const float* Wm1 = (const float*)d_in[18];
    const float* bm1 = (const float*)d_in[19];
    const float* gam = (const float*)d_in[20];
    const float* bet = (const float*)d_in[21];
    const float* bmn = (const float*)d_in[22];
    const float* bvr = (const float*)d_in[23];
    const float* Wm2 = (const float*)d_in[24];
    const float* bm2 = (const float*)d_in[25];

    float* out  = (float*)d_out;
    float* emb1 = out + 32;               // embedding        (16 x 9472)
    float* emb2 = emb1 + NSEG * HID;      // embedding_roi
    float* esum = emb2 + NSEG * HID;      // embedding + embedding_roi

    // ---- workspace carve ----
    char* p = (char*)d_ws;
    auto carve = [&](size_t nbytes) { char* q = p; p += (nbytes + 255) & ~(size_t)255; return (void*)q; };
    int*    row1    = (int*)   carve((N1 + 1) * 4);
    int2*   edges1  = (int2*)  carve((size_t)E1 * 8);
    float*  dinv1   = (float*) carve(N1 * 4);
    __half* A1h     = (__half*)carve((size_t)N1 * HID * 2);   // fp16 h (gemm out)
    __half* B1h     = (__half*)carve((size_t)N1 * HID * 2);   // fp16 conv out
    int*    nodeid1 = (int*)   carve(N1 * 4);
    int*    segrow1 = (int*)   carve((NSEG + 1) * 4);
    int*    segoff  = (int*)   carve(2 * NSEG * 4);           // [0..NSEG) g1, [NSEG..) g2
    int*    bh      = (int*)   carve((NB1 * BLK1 + 1) * 4);
    int*    obh     = (int*)   carve((NB1 * BLK1 + 1) * 4);
    int*    row2    = (int*)   carve((N2 + 1) * 4);
    int*    off2    = (int*)   carve(N2 * 4);
    int2*   edges2  = (int2*)  carve((size_t)E2 * 8);
    float*  dinv2   = (float*) carve(N2 * 4);
    __half* A2h     = (__half*)carve((size_t)N2 * HID * 2);
    __half* B2h     = (__half*)carve((size_t)N2 * HID * 2);
    int*    nodeid2 = (int*)   carve(N2 * 4);
    int*    segrow2 = (int*)   carve((NSEG + 1) * 4);
    int*    part    = (int*)   carve(256 * 4);
    float*  hact    = (float*) carve(BSZ * CLS * 4);
    uint4*  wf1a    = (uint4*) carve(1024 * 16);              // W fragment buffers
    uint4*  wf1b    = (uint4*) carve(512 * 16);
    uint4*  wf2a    = (uint4*) carve(1024 * 16);
    uint4*  wf2b    = (uint4*) carve(512 * 16);
    int*    segoff1 = segoff;
    int*    segoff2 = segoff + NSEG;
    int2*  tmp1 = (int2*)B1h;   // 16.8 MB aliases B1h (16.8 MB): CSR build done
                                // before conv1's first B1h write
    float* clsp = (float*)B1h;  // 4.85 MB partial slabs alias B1h: dead after pool

    const int* src1 = ei1;
    const int* dst1 = ei1 + E1;
    const int* src2 = ei2;
    const int* dst2 = ei2 + E2;

    hipMemsetAsync(d_out, 0, (size_t)out_size * sizeof(float), stream);

    // ---------------- weight fragment prep (independent; overlaps CSR build) ----
    k_wprep<<<12, 256, 0, stream>>>(wf1a, W1a, wf1b, W1b, wf2a, W2a, wf2b, W2b);

    // ---------------- graph 2 CSR (small) ----------------
    hipMemsetAsync(off2, 0, N2 * 4, stream);
    k_hist_dst<<<(E2 + 255) / 256, 256, 0, stream>>>(off2, dst2, E2);
    k_scan_one<<<1, 256, 0, stream>>>(off2, row2, off2, N2, nullptr, nullptr, nullptr, 0);
    k_fill_edges<<<(E2 + 255) / 256, 256, 0, stream>>>(edges2, off2, src2, dst2, ew2, E2);
    k_deg_dinv<<<(N2 + 255) / 256, 256, 0, stream>>>(dinv2, row2, edges2, N2);
    k_scale<<<(N2 + 255) / 256, 256, 0, stream>>>(edges2, row2, dinv2, N2);

    // ---------------- graph 1 CSR: radix-partition build ----------------
    k_p1<<<BLK1, 256, 0, stream>>>(bh, dst1);
    k_scan1<<<(NB1 * BLK1 + 1023) / 1024, 256, 0, stream>>>(bh, obh, part, NB1 * BLK1);
    k_scan2<<<1, 256, 0, stream>>>(part, (NB1 * BLK1 + 1023) / 1024);
    k_scan3<<<(NB1 * BLK1 + 255) / 256, 256, 0, stream>>>(obh, part, NB1 * BLK1, E1);
    k_p2<<<BLK1, 256, 0, stream>>>(tmp1, obh, src1, dst1, ew1);
    k_p3a<<<NB1, 256, 0, stream>>>(row1, dinv1, tmp1, obh);      // row1 built in-kernel
    k_p3b<<<NB1, 256, 0, stream>>>(edges1, tmp1, obh, row1, dinv1);

    // ---------------- fused dense pipeline (both graphs per dispatch) ----------------
    k_gemm<INCH, float><<<GEMMB, 256, 0, stream>>>(A1h, x1, wf1a, T1, A2h, x2, wf2a, T2);
    k_conv<<<CW1 + CW2, 256, 0, stream>>>(B1h, A1h, edges1, row1, dinv1, b1a, N1, CW1,
                                          B2h, A2h, edges2, row2, dinv2, b2a, N2);
    k_gemm<HID, __half><<<GEMMB, 256, 0, stream>>>(A1h, B1h, wf1b, T1, A2h, B2h, wf2b, T2);
    k_conv<<<CW1 + CW2, 256, 0, stream>>>(B1h, A1h, edges1, row1, dinv1, b1b, N1, CW1,
                                          B2h, A2h, edges2, row2, dinv2, b2b, N2);

    // ---------------- segment CSR + pool (both graphs) ----------------
    hipMemsetAsync(segoff, 0, 2 * NSEG * 4, stream);
    k_hist_seg2<<<(N1 + N2 + 255) / 256, 256, 0, stream>>>(segoff1, ba1, nl, N1,
                                                           segoff2, ba2, rl, N2);
    k_scan_one<<<2, 256, 0, stream>>>(segoff1, segrow1, segoff1, NSEG,
                                      segoff2, segrow2, segoff2, NSEG);
    k_fill_seg2<<<(N1 + N2 + 255) / 256, 256, 0, stream>>>(nodeid1, segoff1, ba1, nl, N1,
                                                           nodeid2, segoff2, ba2, rl, N2);
    k_pool<<<PW + PW, 256, 0, stream>>>(emb1, B1h, nodeid1, segrow1, PW,
                                        emb2, B2h, nodeid2, segrow2);
    // B1h dead from here; clsp aliases it

    // ---------------- classifier ----------------
    k_cls<<<KT1 * CT1, 256, 0, stream>>>(clsp, emb1, emb2, esum, Wm1);
    k_credbn<<<(BSZ * CLS + 255) / 256, 256, 0, stream>>>(hact, clsp, bm1, gam, bet, bmn, bvr);
    k_out<<<BSZ, 256, 0, stream>>>(out, hact, Wm2, bm2);
}

// Round 7
// 528.228 us; speedup vs baseline: 1.2030x; 1.0534x over previous
//
#include <hip/hip_runtime.h>
#include <hip/hip_fp16.h>

#define N1 131072
#define E1 2097152
#define N2 2368
#define E2 37888
#define NROIS 148
#define BSZ 16
#define HID 64
#define INCH 128
#define NSEG (BSZ*NROIS)      /* 2368 */
#define SDIM (NROIS*HID)      /* 9472 */
#define CLS 1000
#define OCH 2

#define KT1 148               /* k tiles for k_cls */
#define KCC 64                /* k per tile (148*64 = 9472) */
#define CT1 4                 /* col tiles of 256 */
#define SLP 20                /* LDS slab row stride (floats): 80 B, 16B-aligned */

#define NB1 512               /* dst buckets for graph-1 partition */
#define BLK1 512              /* partition blocks */
#define EPB (E1/BLK1)         /* 4096 edges per block */
#define NPB (N1/NB1)          /* 256 nodes per bucket */

#define CW1 ((N1+15)/16)      /* 8192 conv blocks graph1 (16 nodes/block) */
#define CW2 ((N2+15)/16)      /* 148 conv blocks graph2 */
#define PW  ((NSEG+15)/16)    /* 148 pool blocks per graph */

#define T1 (N1/16)            /* 8192 mfma row-tiles graph1 */
#define T2 (N2/16)            /* 148 mfma row-tiles graph2 */
#define GEMMB ((T1+T2)/4)     /* 2085 gemm blocks (1 tile/wave, 4 waves/block) */

typedef _Float16 h8 __attribute__((ext_vector_type(8)));
typedef float f4 __attribute__((ext_vector_type(4)));

__device__ __forceinline__ unsigned packh2(float a, float b) {
    return (unsigned)__half_as_ushort(__float2half_rn(a)) |
           ((unsigned)__half_as_ushort(__float2half_rn(b)) << 16);
}

// fp32 acc += (f16 half of hb) * w  -- single VALU op, no unpack
__device__ __forceinline__ void fma_lo(float& a, unsigned hb, float w) {
    asm("v_fma_mix_f32 %0, %1, %2, %0 op_sel:[0,0,0] op_sel_hi:[1,0,0]"
        : "+v"(a) : "v"(hb), "v"(w));
}
__device__ __forceinline__ void fma_hi(float& a, unsigned hb, float w) {
    asm("v_fma_mix_f32 %0, %1, %2, %0 op_sel:[1,0,0] op_sel_hi:[1,0,0]"
        : "+v"(a) : "v"(hb), "v"(w));
}

// ---------------- generic small-graph CSR build ----------------

__global__ void k_hist_dst(int* __restrict__ cnt, const int* __restrict__ dst, int E) {
    int e = blockIdx.x * 256 + threadIdx.x;
    if (e < E) atomicAdd(&cnt[dst[e]], 1);
}

__global__ void k_hist_seg2(int* __restrict__ c1, const int* __restrict__ b1,
                            const int* __restrict__ l1, int n1_,
                            int* __restrict__ c2, const int* __restrict__ b2,
                            const int* __restrict__ l2, int n2_) {
    int i = blockIdx.x * 256 + threadIdx.x;
    if (i < n1_) { atomicAdd(&c1[b1[i] * NROIS + l1[i]], 1); return; }
    int j = i - n1_;
    if (j < n2_) atomicAdd(&c2[b2[j] * NROIS + l2[j]], 1);
}

// multi-block exclusive scan (used for the obh bucket histogram)
__global__ void k_scan1(const int* __restrict__ in, int* __restrict__ out,
                        int* __restrict__ part, int n) {
    __shared__ int sh[256];
    int t = threadIdx.x;
    int i0 = blockIdx.x * 1024 + t * 4;
    int v0 = (i0     < n) ? in[i0]     : 0;
    int v1 = (i0 + 1 < n) ? in[i0 + 1] : 0;
    int v2 = (i0 + 2 < n) ? in[i0 + 2] : 0;
    int v3 = (i0 + 3 < n) ? in[i0 + 3] : 0;
    int tot = v0 + v1 + v2 + v3;
    sh[t] = tot; __syncthreads();
    for (int off = 1; off < 256; off <<= 1) {
        int x = 0; if (t >= off) x = sh[t - off];
        __syncthreads();
        if (t >= off) sh[t] += x;
        __syncthreads();
    }
    int excl = sh[t] - tot;
    if (t == 255) part[blockIdx.x] = sh[255];
    if (i0     < n) out[i0]     = excl;
    if (i0 + 1 < n) out[i0 + 1] = excl + v0;
    if (i0 + 2 < n) out[i0 + 2] = excl + v0 + v1;
    if (i0 + 3 < n) out[i0 + 3] = excl + v0 + v1 + v2;
}

__global__ void k_scan2(int* __restrict__ part, int cnt) {
    __shared__ int sh[256];
    int t = threadIdx.x;
    int v = (t < cnt) ? part[t] : 0;
    sh[t] = v; __syncthreads();
    for (int off = 1; off < 256; off <<= 1) {
        int x = 0; if (t >= off) x = sh[t - off];
        __syncthreads();
        if (t >= off) sh[t] += x;
        __syncthreads();
    }
    if (t < cnt) part[t] = sh[t] - v;
}

__global__ void k_scan3(int* __restrict__ out, const int* __restrict__ part, int n, int total) {
    int i = blockIdx.x * 256 + threadIdx.x;
    if (i < n) out[i] += part[i >> 10];
    if (i == 0) out[n] = total;
}

// single-block exclusive scan; block 0 scans set A, block 1 (if in1 != null) set B.
__global__ void k_scan_one(const int* __restrict__ in0, int* __restrict__ out0,
                           int* __restrict__ oo0, int n0,
                           const int* __restrict__ in1, int* __restrict__ out1,
                           int* __restrict__ oo1, int n1_) {
    __shared__ int sh[256];
    __shared__ int carry;
    const int* in; int* out; int* oo; int n;
    if (blockIdx.x == 0) { in = in0; out = out0; oo = oo0; n = n0; }
    else { if (!in1) return; in = in1; out = out1; oo = oo1; n = n1_; }
    int t = threadIdx.x;
    if (t == 0) carry = 0;
    __syncthreads();
    for (int base = 0; base < n; base += 256) {
        int i = base + t;
        int v = (i < n) ? in[i] : 0;
        sh[t] = v; __syncthreads();
        for (int off = 1; off < 256; off <<= 1) {
            int x = 0; if (t >= off) x = sh[t - off];
            __syncthreads();
            if (t >= off) sh[t] += x;
            __syncthreads();
        }
        if (i < n) {
            int e = carry + sh[t] - v;
            out[i] = e;
            if (oo) oo[i] = e;
        }
        __syncthreads();
        if (t == 255) carry += sh[255];
        __syncthreads();
    }
    if (t == 0) out[n] = carry;
}

__global__ void k_fill_edges(int2* __restrict__ edges, int* __restrict__ off,
                             const int* __restrict__ src, const int* __restrict__ dst,
                             const float* __restrict__ ew, int E) {
    int e = blockIdx.x * 256 + threadIdx.x;
    if (e >= E) return;
    int pos = atomicAdd(&off[dst[e]], 1);
    edges[pos] = make_int2(src[e], __float_as_int(ew[e]));
}

// writes PRE-SHIFTED node ids (i << 7 = byte offset of fp16 row) for pool gathers
__global__ void k_fill_seg2(int* __restrict__ id1, int* __restrict__ o1,
                            const int* __restrict__ b1, const int* __restrict__ l1, int n1_,
                            int* __restrict__ id2, int* __restrict__ o2,
                            const int* __restrict__ b2, const int* __restrict__ l2, int n2_) {
    int i = blockIdx.x * 256 + threadIdx.x;
    if (i < n1_) {
        int pos = atomicAdd(&o1[b1[i] * NROIS + l1[i]], 1);
        id1[pos] = i << 7;
        return;
    }
    int j = i - n1_;
    if (j < n2_) {
        int pos = atomicAdd(&o2[b2[j] * NROIS + l2[j]], 1);
        id2[pos] = j << 7;
    }
}

__global__ void k_deg_dinv(float* __restrict__ dinv, const int* __restrict__ row,
                           const int2* __restrict__ edges, int n) {
    int d = blockIdx.x * 256 + threadIdx.x;
    if (d >= n) return;
    int a = row[d], b = row[d + 1];
    float s = 1.0f;
    for (int i = a; i < b; i++) s += __int_as_float(edges[i].y);
    dinv[d] = rsqrtf(s);
}

// scales weights AND pre-shifts src index to byte offset (src << 7)
__global__ void k_scale(int2* __restrict__ edges, const int* __restrict__ row,
                        const float* __restrict__ dinv, int n) {
    int d = blockIdx.x * 256 + threadIdx.x;
    if (d >= n) return;
    int a = row[d], b = row[d + 1];
    float dd = dinv[d];
    for (int i = a; i < b; i++) {
        int2 e = edges[i];
        edges[i] = make_int2(e.x << 7,
                             __float_as_int(dinv[e.x] * __int_as_float(e.y) * dd));
    }
}

// ---------------- graph-1 radix-partition CSR build ----------------

__global__ __launch_bounds__(256) void k_p1(int* __restrict__ bh, const int* __restrict__ dst) {
    __shared__ int cnt[NB1];
    int t = threadIdx.x, blk = blockIdx.x;
    for (int i = t; i < NB1; i += 256) cnt[i] = 0;
    __syncthreads();
    int base = blk * EPB;
    for (int i = t; i < EPB; i += 256) atomicAdd(&cnt[dst[base + i] >> 8], 1);
    __syncthreads();
    for (int b = t; b < NB1; b += 256) bh[b * BLK1 + blk] = cnt[b];   // bucket-major
}

// pack = src (17 bits) | dst_local (8 bits) << 17
__global__ __launch_bounds__(256) void k_p2(int2* __restrict__ tmp, const int* __restrict__ obh,
                                            const int* __restrict__ src,
                                            const int* __restrict__ dst,
                                            const float* __restrict__ ew) {
    __shared__ int cur[NB1];
    int t = threadIdx.x, blk = blockIdx.x;
    for (int b = t; b < NB1; b += 256) cur[b] = obh[b * BLK1 + blk];
    __syncthreads();
    int base = blk * EPB;
    for (int i = t; i < EPB; i += 256) {
        int e = base + i;
        int d = dst[e];
        int pos = atomicAdd(&cur[d >> 8], 1);
        tmp[pos] = make_int2(src[e] | ((d & 255) << 17), __float_as_int(ew[e]));
    }
}

// per-bucket histogram + weight sums; fused local exclusive scan produces row1
__global__ __launch_bounds__(256) void k_p3a(int* __restrict__ row1, float* __restrict__ dinv,
                                             const int2* __restrict__ tmp,
                                             const int* __restrict__ obh) {
    __shared__ int h[NPB];
    __shared__ float ws[NPB];
    __shared__ int sc[256];
    int t = threadIdx.x, b = blockIdx.x;
    h[t] = 0; ws[t] = 0.f;                 // NPB == 256 == blockDim
    __syncthreads();
    int ebase = obh[b * BLK1];
    int eend  = (b == NB1 - 1) ? E1 : obh[(b + 1) * BLK1];
    for (int i = ebase + t; i < eend; i += 256) {
        int2 ed = tmp[i];
        int dl = (ed.x >> 17) & 255;
        atomicAdd(&h[dl], 1);
        atomicAdd(&ws[dl], __int_as_float(ed.y));
    }
    __syncthreads();
    int cnt = h[t];
    sc[t] = cnt; __syncthreads();
    for (int off = 1; off < 256; off <<= 1) {
        int x = 0; if (t >= off) x = sc[t - off];
        __syncthreads();
        if (t >= off) sc[t] += x;
        __syncthreads();
    }
    row1[b * NPB + t] = ebase + sc[t] - cnt;
    dinv[b * NPB + t] = rsqrtf(1.f + ws[t]);
    if (b == NB1 - 1 && t == 255) row1[N1] = E1;
}

// scatter to final CSR; writes PRE-SHIFTED src (byte offset) for conv gathers
__global__ __launch_bounds__(256) void k_p3b(int2* __restrict__ edges,
                                             const int2* __restrict__ tmp,
                                             const int* __restrict__ obh,
                                             const int* __restrict__ row,
                                             const float* __restrict__ dinv) {
    __shared__ int cur[NPB];
    __shared__ float dvl[NPB];
    int t = threadIdx.x, b = blockIdx.x;
    int n0 = b * NPB;
    for (int i = t; i < NPB; i += 256) {
        cur[i] = row[n0 + i];
        dvl[i] = dinv[n0 + i];
    }
    __syncthreads();
    int a  = obh[b * BLK1];
    int e_ = (b == NB1 - 1) ? E1 : obh[(b + 1) * BLK1];
    for (int i = a + t; i < e_; i += 256) {
        int2 ed = tmp[i];
        int dl = (ed.x >> 17) & 255;
        int s = ed.x & 0x1FFFF;
        int pos = atomicAdd(&cur[dl], 1);
        float w = dinv[s] * __int_as_float(ed.y) * dvl[dl];
        edges[pos] = make_int2(s << 7, __float_as_int(w));
    }
}

// ---------------- MFMA gemm ----------------
// out[n][64] = x[n][K] @ W[K][64] via v_mfma_f32_16x16x32_f16.

__device__ __forceinline__ void wfrag(uint4* __restrict__ o, const float* __restrict__ W,
                                      int KCH, int idx) {
    int lane = idx & 63;
    int rest = idx >> 6;
    int ch = rest % KCH;
    int ct = rest / KCH;
    int kr = ch * 32 + ((lane >> 4) * 8);
    int col = ct * 16 + (lane & 15);
    const float* wp = W + (size_t)kr * 64 + col;
    o[idx] = make_uint4(packh2(wp[0],   wp[64]),
                        packh2(wp[128], wp[192]),
                        packh2(wp[256], wp[320]),
                        packh2(wp[384], wp[448]));
}

__global__ void k_wprep(uint4* __restrict__ wf1a, const float* __restrict__ W1a,
                        uint4* __restrict__ wf1b, const float* __restrict__ W1b,
                        uint4* __restrict__ wf2a, const float* __restrict__ W2a,
                        uint4* __restrict__ wf2b, const float* __restrict__ W2b) {
    int idx = blockIdx.x * 256 + threadIdx.x;
    if      (idx < 1024) wfrag(wf1a, W1a, 4, idx);
    else if (idx < 1536) wfrag(wf1b, W1b, 2, idx - 1024);
    else if (idx < 2560) wfrag(wf2a, W2a, 4, idx - 1536);
    else if (idx < 3072) wfrag(wf2b, W2b, 2, idx - 2560);
}

__device__ __forceinline__ h8 loadA(const float* p) {
    float4 a = *(const float4*)p;
    float4 b = *(const float4*)(p + 4);
    union { h8 v; __half h[8]; } u;
    u.h[0] = __float2half_rn(a.x); u.h[1] = __float2half_rn(a.y);
    u.h[2] = __float2half_rn(a.z); u.h[3] = __float2half_rn(a.w);
    u.h[4] = __float2half_rn(b.x); u.h[5] = __float2half_rn(b.y);
    u.h[6] = __float2half_rn(b.z); u.h[7] = __float2half_rn(b.w);
    return u.v;
}
__device__ __forceinline__ h8 loadA(const __half* p) {
    union { h8 v; uint4 u; } u;
    u.u = *(const uint4*)p;
    return u.v;
}

template <int K, typename T>
__global__ __launch_bounds__(256) void k_gemm(__half* __restrict__ out1, const T* __restrict__ x1,
                                              const uint4* __restrict__ wfa, int t1,
                                              __half* __restrict__ out2, const T* __restrict__ x2,
                                              const uint4* __restrict__ wfb, int t2) {
    constexpr int KCH = K / 32;
    int wid = blockIdx.x * 4 + (threadIdx.x >> 6);
    int lane = threadIdx.x & 63;
    __half* out; const T* x; const uint4* wf; int row0;
    if (wid < t1) { out = out1; x = x1; wf = wfa; row0 = wid * 16; }
    else {
        int w2 = wid - t1;
        if (w2 >= t2) return;
        out = out2; x = x2; wf = wfb; row0 = w2 * 16;
    }
    int lrow = lane & 15, lg = lane >> 4;

    h8 bf[4][KCH];
#pragma unroll
    for (int ct = 0; ct < 4; ct++)
#pragma unroll
        for (int ch = 0; ch < KCH; ch++) {
            union { h8 v; uint4 u; } u;
            u.u = wf[(ct * KCH + ch) * 64 + lane];
            bf[ct][ch] = u.v;
        }

    const T* xr = x + (size_t)(row0 + lrow) * K + lg * 8;
    h8 af[KCH];
#pragma unroll
    for (int ch = 0; ch < KCH; ch++) af[ch] = loadA(xr + ch * 32);

    f4 acc[4];
#pragma unroll
    for (int ct = 0; ct < 4; ct++) acc[ct] = (f4){0.f, 0.f, 0.f, 0.f};
#pragma unroll
    for (int ch = 0; ch < KCH; ch++)
#pragma unroll
        for (int ct = 0; ct < 4; ct++)
            acc[ct] = __builtin_amdgcn_mfma_f32_16x16x32_f16(af[ch], bf[ct][ch], acc[ct], 0, 0, 0);

#pragma unroll
    for (int ct = 0; ct < 4; ct++)
#pragma unroll
        for (int r = 0; r < 4; r++)
            out[(size_t)(row0 + lg * 4 + r) * 64 + ct * 16 + lrow] = __float2half_rn(acc[ct][r]);
}

// ---------------- conv / pool (4 nodes/wave, 16 lanes/node, uint4 gathers) ----------------
__device__ __forceinline__ void conv_wave(__half* __restrict__ out, const __half* __restrict__ h,
                                          const int2* __restrict__ edges,
                                          const int* __restrict__ row,
                                          const float* __restrict__ dinv,
                                          const float* __restrict__ bias,
                                          int d0, int n, int lane) {
    int g  = lane >> 4;           // node slot 0..3
    int fl = lane & 15;
    int eh = fl >> 3;             // edge half 0/1
    int f8 = fl & 7;              // feature octet: features f8*8 .. f8*8+7
    int d  = d0 + g;
    bool vn = d < n;
    int a = 0, b = 0;
    if (vn) { a = row[d]; b = row[d + 1]; }
    const char* hb = (const char*)h + f8 * 16;
    float acc[8] = {0.f,0.f,0.f,0.f,0.f,0.f,0.f,0.f};

    for (int base = a; base < b; base += 16) {
        int sv = 0, wv = 0;       // zero-pad: w=0 kills invalid contributions
        if (base + fl < b) { int2 e = edges[base + fl]; sv = e.x; wv = e.y; }
        int mm = b - base; if (mm > 16) mm = 16;
        int steps = (mm + 1) >> 1;
        int idx = (g << 4) + eh;
        for (int t = 0; t < steps; t++) {
            int   s = __shfl(sv, idx + (t << 1));
            float w = __int_as_float(__shfl(wv, idx + (t << 1)));
            uint4 hv = *(const uint4*)(hb + (unsigned)s);
            fma_lo(acc[0], hv.x, w); fma_hi(acc[1], hv.x, w);
            fma_lo(acc[2], hv.y, w); fma_hi(acc[3], hv.y, w);
            fma_lo(acc[4], hv.z, w); fma_hi(acc[5], hv.z, w);
            fma_lo(acc[6], hv.w, w); fma_hi(acc[7], hv.w, w);
        }
    }
    float r[8];
#pragma unroll
    for (int f = 0; f < 8; f++) r[f] = acc[f] + __shfl_xor(acc[f], 8);
    if (vn && eh == 0) {
        float di = dinv[d];
        float sl = di * di;
        uint4 hd = *(const uint4*)(hb + ((unsigned)d << 7));
        fma_lo(r[0], hd.x, sl); fma_hi(r[1], hd.x, sl);
        fma_lo(r[2], hd.y, sl); fma_hi(r[3], hd.y, sl);
        fma_lo(r[4], hd.z, sl); fma_hi(r[5], hd.z, sl);
        fma_lo(r[6], hd.w, sl); fma_hi(r[7], hd.w, sl);
        float4 b0 = *(const float4*)(bias + f8 * 8);
        float4 b1 = *(const float4*)(bias + f8 * 8 + 4);
        uint4 ov;
        ov.x = packh2(fmaxf(r[0] + b0.x, 0.f), fmaxf(r[1] + b0.y, 0.f));
        ov.y = packh2(fmaxf(r[2] + b0.z, 0.f), fmaxf(r[3] + b0.w, 0.f));
        ov.z = packh2(fmaxf(r[4] + b1.x, 0.f), fmaxf(r[5] + b1.y, 0.f));
        ov.w = packh2(fmaxf(r[6] + b1.z, 0.f), fmaxf(r[7] + b1.w, 0.f));
        *(uint4*)(out + (size_t)d * HID + f8 * 8) = ov;
    }
}

__global__ __launch_bounds__(256) void k_conv(__half* __restrict__ o1, const __half* __restrict__ h1,
                                              const int2* __restrict__ e1, const int* __restrict__ r1,
                                              const float* __restrict__ dv1, const float* __restrict__ bi1,
                                              int n1_, int nb1_,
                                              __half* __restrict__ o2, const __half* __restrict__ h2,
                                              const int2* __restrict__ e2, const int* __restrict__ r2,
                                              const float* __restrict__ dv2, const float* __restrict__ bi2,
                                              int n2_) {
    int blk = blockIdx.x;
    int lane = threadIdx.x & 63;
    int wv = threadIdx.x >> 6;
    if (blk < nb1_) conv_wave(o1, h1, e1, r1, dv1, bi1, blk * 16 + wv * 4, n1_, lane);
    else            conv_wave(o2, h2, e2, r2, dv2, bi2, (blk - nb1_) * 16 + wv * 4, n2_, lane);
}

// segment-mean pool, same wave structure (weight 1 / 0-masked).
__device__ __forceinline__ void pool_wave(float* __restrict__ emb, const __half* __restrict__ h,
                                          const int* __restrict__ nodeid,
                                          const int* __restrict__ segrow, int s0, int lane) {
    int g  = lane >> 4;
    int fl = lane & 15;
    int eh = fl >> 3;
    int f8 = fl & 7;
    int s  = s0 + g;
    bool vs = s < NSEG;
    int a = 0, b = 0;
    if (vs) { a = segrow[s]; b = segrow[s + 1]; }
    const char* hb = (const char*)h + f8 * 16;
    float acc[8] = {0.f,0.f,0.f,0.f,0.f,0.f,0.f,0.f};

    for (int base = a; base < b; base += 16) {
        int sv = 0, wv = 0;
        if (base + fl < b) { sv = nodeid[base + fl]; wv = 0x3f800000; }
        int mm = b - base; if (mm > 16) mm = 16;
        int steps = (mm + 1) >> 1;
        int idx = (g << 4) + eh;
        for (int t = 0; t < steps; t++) {
            int   q = __shfl(sv, idx + (t << 1));
            float w = __int_as_float(__shfl(wv, idx + (t << 1)));
            uint4 hv = *(const uint4*)(hb + (unsigned)q);
            fma_lo(acc[0], hv.x, w); fma_hi(acc[1], hv.x, w);
            fma_lo(acc[2], hv.y, w); fma_hi(acc[3], hv.y, w);
            fma_lo(acc[4], hv.z, w); fma_hi(acc[5], hv.z, w);
            fma_lo(acc[6], hv.w, w); fma_hi(acc[7], hv.w, w);
        }
    }
    float r[8];
#pragma unroll
    for (int f = 0; f < 8; f++) r[f] = acc[f] + __shfl_xor(acc[f], 8);
    if (vs && eh == 0) {
        float inv = 1.0f / fmaxf((float)(b - a), 1.0f);
        float4 lo = make_float4(r[0] * inv, r[1] * inv, r[2] * inv, r[3] * inv);
        float4 hi = make_float4(r[4] * inv, r[5] * inv, r[6] * inv, r[7] * inv);
        *(float4*)(emb + (size_t)s * HID + f8 * 8)     = lo;
        *(float4*)(emb + (size_t)s * HID + f8 * 8 + 4) = hi;
    }
}

__global__ __launch_bounds__(256) void k_pool(float* __restrict__ em1, const __half* __restrict__ h1,
                                              const int* __restrict__ id1, const int* __restrict__ sr1,
                                              int nbs,
                                              float* __restrict__ em2, const __half* __restrict__ h2,
                                              const int* __restrict__ id2, const int* __restrict__ sr2) {
    int blk = blockIdx.x;
    int lane = threadIdx.x & 63;
    int wv = threadIdx.x >> 6;
    if (blk < nbs) pool_wave(em1, h1, id1, sr1, blk * 16 + wv * 4, lane);
    else           pool_wave(em2, h2, id2, sr2, (blk - nbs) * 16 + wv * 4, lane);
}

// ---------------- classifier ----------------

// v2: 592 blocks (KT1=148 x CT1=4), all-W-preload (64 loads in flight/thread),
// stride-20 LDS slab (aligned float4, conflict-free-ish writes, broadcast reads).
__global__ __launch_bounds__(256) void k_cls(float* __restrict__ part_,
                                             const float* __restrict__ e1,
                                             const float* __restrict__ e2,
                                             float* __restrict__ esum,
                                             const float* __restrict__ Wm1) {
    __shared__ float sl[KCC * SLP];     // [kk][b], row stride SLP=20 floats
    int tid = threadIdx.x;
    int kt = blockIdx.x >> 2, ct = blockIdx.x & 3;
    int k0 = kt * KCC;
    bool wr = (ct == 0);
    for (int i = tid; i < KCC * 16; i += 256) {
        int kk = i & (KCC - 1), b = i >> 6;        // coalesced over kk
        int idx = b * SDIM + k0 + kk;
        float v = e1[idx] + e2[idx];
        sl[kk * SLP + b] = v;
        if (wr) esum[idx] = v;
    }
    __syncthreads();
    int c = ct * 256 + tid;
    bool active = c < CLS;
    const float* wp = Wm1 + (size_t)k0 * CLS + c;
    float wv[KCC];
#pragma unroll
    for (int kk = 0; kk < KCC; kk++)
        wv[kk] = active ? wp[(size_t)kk * CLS] : 0.f;   // 64 independent loads in flight
    float acc[16];
#pragma unroll
    for (int b = 0; b < 16; b++) acc[b] = 0.f;
#pragma unroll
    for (int kk = 0; kk < KCC; kk++) {
        float w = wv[kk];
        float4 s0 = *(const float4*)(&sl[kk * SLP + 0]);
        float4 s1 = *(const float4*)(&sl[kk * SLP + 4]);
        float4 s2 = *(const float4*)(&sl[kk * SLP + 8]);
        float4 s3 = *(const float4*)(&sl[kk * SLP + 12]);
        acc[0]  += s0.x * w; acc[1]  += s0.y * w; acc[2]  += s0.z * w; acc[3]  += s0.w * w;
        acc[4]  += s1.x * w; acc[5]  += s1.y * w; acc[6]  += s1.z * w; acc[7]  += s1.w * w;
        acc[8]  += s2.x * w; acc[9]  += s2.y * w; acc[10] += s2.z * w; acc[11] += s2.w * w;
        acc[12] += s3.x * w; acc[13] += s3.y * w; acc[14] += s3.z * w; acc[15] += s3.w * w;
    }
    float* pp = part_ + (size_t)(kt * CT1 + ct) * 16 * 256;
#pragma unroll
    for (int b = 0; b < 16; b++) pp[b * 256 + tid] = acc[b];
}

// reduce partials + BatchNorm + LeakyReLU in one pass
__global__ void k_credbn(float* __restrict__ hact, const float* __restrict__ part_,
                         const float* __restrict__ bm1, const float* __restrict__ gamma,
                         const float* __restrict__ beta, const float* __restrict__ mean,
                         const float* __restrict__ var) {
    int idx = blockIdx.x * 256 + threadIdx.x;
    if (idx >= BSZ * CLS) return;
    int b = idx / CLS, c = idx % CLS;
    int ct = c >> 8, cl = c & 255;
    float sum = 0.f;
#pragma unroll 8
    for (int kt = 0; kt < KT1; kt++)
        sum += part_[((size_t)(kt * CT1 + ct) * 16 + b) * 256 + cl];
    float t = sum + bm1[c];
    t = gamma[c] * (t - mean[c]) * rsqrtf(var[c] + 1e-5f) + beta[c];
    hact[idx] = t > 0.f ? t : 0.01f * t;
}

// one block per batch row; 128 partials per output
__global__ void k_out(float* __restrict__ outp, const float* __restrict__ hact,
                      const float* __restrict__ Wm2, const float* __restrict__ bm2) {
    int b = blockIdx.x;
    int tid = threadIdx.x;
    int o = tid & 1, part = tid >> 1;   // 2 outputs x 128 partials
    float acc = (part == 0) ? bm2[o] : 0.f;
    for (int k = part; k < CLS; k += 128) acc += hact[b * CLS + k] * Wm2[k * OCH + o];
    unsafeAtomicAdd(&outp[b * OCH + o], acc);
}

extern "C" void kernel_launch(void* const* d_in, const int* in_sizes, int n_in,
                              void* d_out, int out_size, void* d_ws, size_t ws_size,
                              hipStream_t stream) {
    const float* x1  = (const float*)d_in[0];
    const int*   nl  = (const int*)d_in[1];
    const int*   ei1 = (const int*)d_in[2];
    const float* ew1 = (const float*)d_in[3];
    const int*   ba1 = (const int*)d_in[4];
    const float* x2  = (const float*)d_in[5];
    const int*   rl  = (const int*)d_in[6];
    const int*   ei2 = (const int*)d_in[7];
    const float* ew2 = (const float*)d_in[8];
    const int*   ba2 = (const int*)d_in[9];
    const float* W1a = (const float*)d_in[10];
    const float* b1a = (const float*)d_in[11];
    const float* W1b = (const float*)d_in[12];
    const float* b1b = (const float*)d_in[13];
    const float* W2a = (const float*)d_in[14];
    const float* b2a = (const float*)d_in[15];
    const float* W2b = (const float*)d_in[16];
    const float* b2b = (const float*)d_in[17];
    const float* Wm1 = (const float*)d_in[18];
    const float* bm1 = (const float*)d_in[19];
    const float* gam = (const float*)d_in[20];
    const float* bet = (const float*)d_in[21];
    const float* bmn = (const float*)d_in[22];
    const float* bvr = (const float*)d_in[23];
    const float* Wm2 = (const float*)d_in[24];
    const float* bm2 = (const float*)d_in[25];

    float* out  = (float*)d_out;
    float* emb1 = out + 32;               // embedding        (16 x 9472)
    float* emb2 = emb1 + NSEG * HID;      // embedding_roi
    float* esum = emb2 + NSEG * HID;      // embedding + embedding_roi

    // ---- workspace carve ----
    char* p = (char*)d_ws;
    auto carve = [&](size_t nbytes) { char* q = p; p += (nbytes + 255) & ~(size_t)255; return (void*)q; };
    int*    row1    = (int*)   carve((N1 + 1) * 4);
    int2*   edges1  = (int2*)  carve((size_t)E1 * 8);
    float*  dinv1   = (float*) carve(N1 * 4);
    __half* A1h     = (__half*)carve((size_t)N1 * HID * 2);   // fp16 h (gemm out)
    __half* B1h     = (__half*)carve((size_t)N1 * HID * 2);   // fp16 conv out
    int*    nodeid1 = (int*)   carve(N1 * 4);
    int*    segrow1 = (int*)   carve((NSEG + 1) * 4);
    int*    segoff  = (int*)   carve(2 * NSEG * 4);           // [0..NSEG) g1, [NSEG..) g2
    int*    bh      = (int*)   carve((NB1 * BLK1 + 1) * 4);
    int*    obh     = (int*)   carve((NB1 * BLK1 + 1) * 4);
    int*    row2    = (int*)   carve((N2 + 1) * 4);
    int*    off2    = (int*)   carve(N2 * 4);
    int2*   edges2  = (int2*)  carve((size_t)E2 * 8);
    float*  dinv2   = (float*) carve(N2 * 4);
    __half* A2h     = (__half*)carve((size_t)N2 * HID * 2);
    __half* B2h     = (__half*)carve((size_t)N2 * HID * 2);
    int*    nodeid2 = (int*)   carve(N2 * 4);
    int*    segrow2 = (int*)   carve((NSEG + 1) * 4);
    int*    part    = (int*)   carve(256 * 4);
    float*  hact    = (float*) carve(BSZ * CLS * 4);
    uint4*  wf1a    = (uint4*) carve(1024 * 16);              // W fragment buffers
    uint4*  wf1b    = (uint4*) carve(512 * 16);
    uint4*  wf2a    = (uint4*) carve(1024 * 16);
    uint4*  wf2b    = (uint4*) carve(512 * 16);
    int*    segoff1 = segoff;
    int*    segoff2 = segoff + NSEG;
    int2*  tmp1 = (int2*)B1h;   // 16.8 MB aliases B1h (16.8 MB): CSR build done
                                // before conv1's first B1h write
    float* clsp = (float*)B1h;  // 9.7 MB partial slabs alias B1h: dead after pool

    const int* src1 = ei1;
    const int* dst1 = ei1 + E1;
    const int* src2 = ei2;
    const int* dst2 = ei2 + E2;

    hipMemsetAsync(d_out, 0, (size_t)out_size * sizeof(float), stream);

    // ---------------- weight fragment prep (independent; overlaps CSR build) ----
    k_wprep<<<12, 256, 0, stream>>>(wf1a, W1a, wf1b, W1b, wf2a, W2a, wf2b, W2b);

    // ---------------- graph 2 CSR (small) ----------------
    hipMemsetAsync(off2, 0, N2 * 4, stream);
    k_hist_dst<<<(E2 + 255) / 256, 256, 0, stream>>>(off2, dst2, E2);
    k_scan_one<<<1, 256, 0, stream>>>(off2, row2, off2, N2, nullptr, nullptr, nullptr, 0);
    k_fill_edges<<<(E2 + 255) / 256, 256, 0, stream>>>(edges2, off2, src2, dst2, ew2, E2);
    k_deg_dinv<<<(N2 + 255) / 256, 256, 0, stream>>>(dinv2, row2, edges2, N2);
    k_scale<<<(N2 + 255) / 256, 256, 0, stream>>>(edges2, row2, dinv2, N2);

    // ---------------- graph 1 CSR: radix-partition build ----------------
    k_p1<<<BLK1, 256, 0, stream>>>(bh, dst1);
    k_scan1<<<(NB1 * BLK1 + 1023) / 1024, 256, 0, stream>>>(bh, obh, part, NB1 * BLK1);
    k_scan2<<<1, 256, 0, stream>>>(part, (NB1 * BLK1 + 1023) / 1024);
    k_scan3<<<(NB1 * BLK1 + 255) / 256, 256, 0, stream>>>(obh, part, NB1 * BLK1, E1);
    k_p2<<<BLK1, 256, 0, stream>>>(tmp1, obh, src1, dst1, ew1);
    k_p3a<<<NB1, 256, 0, stream>>>(row1, dinv1, tmp1, obh);      // row1 built in-kernel
    k_p3b<<<NB1, 256, 0, stream>>>(edges1, tmp1, obh, row1, dinv1);

    // ---------------- fused dense pipeline (both graphs per dispatch) ----------------
    k_gemm<INCH, float><<<GEMMB, 256, 0, stream>>>(A1h, x1, wf1a, T1, A2h, x2, wf2a, T2);
    k_conv<<<CW1 + CW2, 256, 0, stream>>>(B1h, A1h, edges1, row1, dinv1, b1a, N1, CW1,
                                          B2h, A2h, edges2, row2, dinv2, b2a, N2);
    k_gemm<HID, __half><<<GEMMB, 256, 0, stream>>>(A1h, B1h, wf1b, T1, A2h, B2h, wf2b, T2);
    k_conv<<<CW1 + CW2, 256, 0, stream>>>(B1h, A1h, edges1, row1, dinv1, b1b, N1, CW1,
                                          B2h, A2h, edges2, row2, dinv2, b2b, N2);

    // ---------------- segment CSR + pool (both graphs) ----------------
    hipMemsetAsync(segoff, 0, 2 * NSEG * 4, stream);
    k_hist_seg2<<<(N1 + N2 + 255) / 256, 256, 0, stream>>>(segoff1, ba1, nl, N1,
                                                           segoff2, ba2, rl, N2);
    k_scan_one<<<2, 256, 0, stream>>>(segoff1, segrow1, segoff1, NSEG,
                                      segoff2, segrow2, segoff2, NSEG);
    k_fill_seg2<<<(N1 + N2 + 255) / 256, 256, 0, stream>>>(nodeid1, segoff1, ba1, nl, N1,
                                                           nodeid2, segoff2, ba2, rl, N2);
    k_pool<<<PW + PW, 256, 0, stream>>>(emb1, B1h, nodeid1, segrow1, PW,
                                        emb2, B2h, nodeid2, segrow2);
    // B1h dead from here; clsp aliases it

    // ---------------- classifier ----------------
    k_cls<<<KT1 * CT1, 256, 0, stream>>>(clsp, emb1, emb2, esum, Wm1);
    k_credbn<<<(BSZ * CLS + 255) / 256, 256, 0, stream>>>(hact, clsp, bm1, gam, bet, bmn, bvr);
    k_out<<<BSZ, 256, 0, stream>>>(out, hact, Wm2, bm2);
}